// Round 1
// baseline (964.226 us; speedup 1.0000x reference)
//
#include <hip/hip_runtime.h>
#include <stdint.h>

#define DIN 128
#define DOUT 128
#define LN_EPS 1e-5f

// Monotone float->uint encoding: preserves order under unsigned max.
__device__ __forceinline__ uint32_t enc_f32(float f) {
  uint32_t u = __float_as_uint(f);
  return u ^ (0x80000000u | (uint32_t)(-(int32_t)(u >> 31)));
}
__device__ __forceinline__ float dec_f32(uint32_t e) {
  uint32_t u = (e & 0x80000000u) ? (e & 0x7FFFFFFFu) : ~e;
  return __uint_as_float(u);
}
#define ENC_NEG_INF 0x007FFFFFu  // enc(-inf)

__global__ __launch_bounds__(256) void k_init(uint32_t* __restrict__ M, int n) {
  int i = blockIdx.x * 256 + threadIdx.x;
  if (i < n) M[i] = ENC_NEG_INF;
}

// P[N,128] = vf[N,128] @ W_edge[128,128]
__global__ __launch_bounds__(256) void k_gemm_vf(const float* __restrict__ vf,
                                                 const float* __restrict__ W,
                                                 float* __restrict__ P, int N) {
  __shared__ float Wl[DIN * DOUT];     // 64 KB
  __shared__ float rowbuf[4][DIN];
  for (int i = threadIdx.x * 4; i < DIN * DOUT; i += 256 * 4)
    *(float4*)(&Wl[i]) = *(const float4*)(&W[i]);
  int wave = threadIdx.x >> 6, lane = threadIdx.x & 63;
  int ntiles = (N + 3) >> 2;
  for (int tile = blockIdx.x; tile < ntiles; tile += gridDim.x) {
    int row0 = tile * 4;
    __syncthreads();
    {
      int r = threadIdx.x >> 6, i2 = threadIdx.x & 63;
      int row = row0 + r;
      float2 v = make_float2(0.f, 0.f);
      if (row < N) v = *(const float2*)(vf + (size_t)row * DIN + i2 * 2);
      *(float2*)(&rowbuf[r][i2 * 2]) = v;
    }
    __syncthreads();
    int row = row0 + wave;
    if (row < N) {
      float acc0 = 0.f, acc1 = 0.f;
      const float* rb = rowbuf[wave];
#pragma unroll 8
      for (int i = 0; i < DIN; ++i) {
        float c = rb[i];
        float2 w = *(const float2*)(&Wl[i * DOUT + lane * 2]);
        acc0 = fmaf(c, w.x, acc0);
        acc1 = fmaf(c, w.y, acc1);
      }
      *(float2*)(P + (size_t)row * DOUT + lane * 2) = make_float2(acc0, acc1);
    }
  }
}

// scatter-max: M[dst] = max(M[dst], P[src]) elementwise (encoded uints)
__global__ __launch_bounds__(256) void k_scatter(const float* __restrict__ P,
                                                 const int* __restrict__ ei,
                                                 uint32_t* __restrict__ M, int E) {
  int gid = blockIdx.x * 256 + threadIdx.x;
  int e = gid >> 5;
  if (e >= E) return;
  int t = threadIdx.x & 31;
  int s = ei[e];
  int d = ei[E + e];
  const float4 p = ((const float4*)(P + (size_t)s * DOUT))[t];
  uint32_t* mrow = M + (size_t)d * DOUT + t * 4;
  uint4 cur = *(const uint4*)mrow;  // stale-read OK: M monotone under max
  uint32_t e0 = enc_f32(p.x); if (e0 > cur.x) atomicMax(&mrow[0], e0);
  uint32_t e1 = enc_f32(p.y); if (e1 > cur.y) atomicMax(&mrow[1], e1);
  uint32_t e2 = enc_f32(p.z); if (e2 > cur.z) atomicMax(&mrow[2], e2);
  uint32_t e3 = enc_f32(p.w); if (e3 > cur.w) atomicMax(&mrow[3], e3);
}

// h[N,128] = relu(LN(concat(vf, agg) @ W1 + b1))
__global__ __launch_bounds__(256) void k_mlp1(
    const float* __restrict__ vf, const uint32_t* __restrict__ M,
    const float* __restrict__ P, const float* __restrict__ b_edge,
    const float* __restrict__ W1, const float* __restrict__ b1,
    const float* __restrict__ gamma, const float* __restrict__ beta,
    float* __restrict__ h, int N) {
  __shared__ float Wl[256 * DOUT];   // 128 KB
  __shared__ float rowbuf[4][256];   // 4 KB
  for (int i = threadIdx.x * 4; i < 256 * DOUT; i += 256 * 4)
    *(float4*)(&Wl[i]) = *(const float4*)(&W1[i]);
  int wave = threadIdx.x >> 6, lane = threadIdx.x & 63;
  int ntiles = (N + 3) >> 2;
  for (int tile = blockIdx.x; tile < ntiles; tile += gridDim.x) {
    int row0 = tile * 4;
    __syncthreads();
    for (int idx = threadIdx.x; idx < 4 * 256; idx += 256) {
      int r = idx >> 8, i = idx & 255;
      int row = row0 + r;
      float v = 0.f;
      if (row < N) {
        if (i < DIN) {
          v = vf[(size_t)row * DIN + i];
        } else {
          int j = i - DIN;
          uint32_t m = M[(size_t)row * DOUT + j];
          v = (m == ENC_NEG_INF)
                  ? 0.f
                  : dec_f32(m) - P[(size_t)row * DOUT + j] + b_edge[j];
        }
      }
      rowbuf[r][i] = v;
    }
    __syncthreads();
    int row = row0 + wave;
    if (row < N) {
      float acc0 = 0.f, acc1 = 0.f;
      const float* rb = rowbuf[wave];
#pragma unroll 8
      for (int i = 0; i < 256; ++i) {
        float c = rb[i];
        float2 w = *(const float2*)(&Wl[i * DOUT + lane * 2]);
        acc0 = fmaf(c, w.x, acc0);
        acc1 = fmaf(c, w.y, acc1);
      }
      float h0 = acc0 + b1[lane * 2];
      float h1 = acc1 + b1[lane * 2 + 1];
      float s = h0 + h1, sq = h0 * h0 + h1 * h1;
#pragma unroll
      for (int m_ = 32; m_ >= 1; m_ >>= 1) {
        s += __shfl_xor(s, m_, 64);
        sq += __shfl_xor(sq, m_, 64);
      }
      float mu = s * (1.f / 128.f);
      float var = sq * (1.f / 128.f) - mu * mu;
      float rs = rsqrtf(var + LN_EPS);
      float o0 = fmaxf(fmaf((h0 - mu) * rs, gamma[lane * 2], beta[lane * 2]), 0.f);
      float o1 = fmaxf(fmaf((h1 - mu) * rs, gamma[lane * 2 + 1], beta[lane * 2 + 1]), 0.f);
      *(float2*)(h + (size_t)row * DOUT + lane * 2) = make_float2(o0, o1);
    }
  }
}

// out[N,128] = h @ W2 + b2
__global__ __launch_bounds__(256) void k_mlp2(const float* __restrict__ h,
                                              const float* __restrict__ W2,
                                              const float* __restrict__ b2,
                                              float* __restrict__ out, int N) {
  __shared__ float Wl[DOUT * DOUT];  // 64 KB
  __shared__ float rowbuf[4][DOUT];
  for (int i = threadIdx.x * 4; i < DOUT * DOUT; i += 256 * 4)
    *(float4*)(&Wl[i]) = *(const float4*)(&W2[i]);
  int wave = threadIdx.x >> 6, lane = threadIdx.x & 63;
  int ntiles = (N + 3) >> 2;
  for (int tile = blockIdx.x; tile < ntiles; tile += gridDim.x) {
    int row0 = tile * 4;
    __syncthreads();
    {
      int r = threadIdx.x >> 6, i2 = threadIdx.x & 63;
      int row = row0 + r;
      float2 v = make_float2(0.f, 0.f);
      if (row < N) v = *(const float2*)(h + (size_t)row * DOUT + i2 * 2);
      *(float2*)(&rowbuf[r][i2 * 2]) = v;
    }
    __syncthreads();
    int row = row0 + wave;
    if (row < N) {
      float acc0 = b2[lane * 2];
      float acc1 = b2[lane * 2 + 1];
      const float* rb = rowbuf[wave];
#pragma unroll 8
      for (int i = 0; i < DOUT; ++i) {
        float c = rb[i];
        float2 w = *(const float2*)(&Wl[i * DOUT + lane * 2]);
        acc0 = fmaf(c, w.x, acc0);
        acc1 = fmaf(c, w.y, acc1);
      }
      *(float2*)(out + (size_t)row * DOUT + lane * 2) = make_float2(acc0, acc1);
    }
  }
}

extern "C" void kernel_launch(void* const* d_in, const int* in_sizes, int n_in,
                              void* d_out, int out_size, void* d_ws, size_t ws_size,
                              hipStream_t stream) {
  const float* vf     = (const float*)d_in[0];
  const int*   ei     = (const int*)d_in[1];
  const float* W_edge = (const float*)d_in[2];
  const float* b_edge = (const float*)d_in[3];
  const float* W1     = (const float*)d_in[4];
  const float* b1     = (const float*)d_in[5];
  const float* gamma  = (const float*)d_in[6];
  const float* beta   = (const float*)d_in[7];
  const float* W2     = (const float*)d_in[8];
  const float* b2     = (const float*)d_in[9];
  float* out = (float*)d_out;

  int N = in_sizes[0] / DIN;
  int E = in_sizes[1] / 2;

  char* ws = (char*)d_ws;
  size_t seg = (size_t)N * DOUT * sizeof(float);
  float*    P  = (float*)ws;
  uint32_t* M  = (uint32_t*)(ws + seg);
  float*    hb = (float*)(ws + 2 * seg);

  int nM = N * DOUT;
  k_init<<<(nM + 255) / 256, 256, 0, stream>>>(M, nM);
  k_gemm_vf<<<2048, 256, 0, stream>>>(vf, W_edge, P, N);
  int eblocks = ((E * 32) + 255) / 256;
  k_scatter<<<eblocks, 256, 0, stream>>>(P, ei, M, E);
  k_mlp1<<<256, 256, 0, stream>>>(vf, M, P, b_edge, W1, b1, gamma, beta, hb, N);
  k_mlp2<<<512, 256, 0, stream>>>(hb, W2, b2, out, N);
}

// Round 2
// 548.031 us; speedup vs baseline: 1.7594x; 1.7594x over previous
//
#include <hip/hip_runtime.h>
#include <stdint.h>

#define DIN 128
#define DOUT 128
#define LN_EPS 1e-5f

__global__ __launch_bounds__(256) void k_gemm_vf(const float* __restrict__ vf,
                                                 const float* __restrict__ W,
                                                 float* __restrict__ P, int N) {
  __shared__ float Wl[DIN * DOUT];     // 64 KB
  __shared__ float rowbuf[4][DIN];
  for (int i = threadIdx.x * 4; i < DIN * DOUT; i += 256 * 4)
    *(float4*)(&Wl[i]) = *(const float4*)(&W[i]);
  int wave = threadIdx.x >> 6, lane = threadIdx.x & 63;
  int ntiles = (N + 3) >> 2;
  for (int tile = blockIdx.x; tile < ntiles; tile += gridDim.x) {
    int row0 = tile * 4;
    __syncthreads();
    {
      int r = threadIdx.x >> 6, i2 = threadIdx.x & 63;
      int row = row0 + r;
      float2 v = make_float2(0.f, 0.f);
      if (row < N) v = *(const float2*)(vf + (size_t)row * DIN + i2 * 2);
      *(float2*)(&rowbuf[r][i2 * 2]) = v;
    }
    __syncthreads();
    int row = row0 + wave;
    if (row < N) {
      float acc0 = 0.f, acc1 = 0.f;
      const float* rb = rowbuf[wave];
#pragma unroll 8
      for (int i = 0; i < DIN; ++i) {
        float c = rb[i];
        float2 w = *(const float2*)(&Wl[i * DOUT + lane * 2]);
        acc0 = fmaf(c, w.x, acc0);
        acc1 = fmaf(c, w.y, acc1);
      }
      *(float2*)(P + (size_t)row * DOUT + lane * 2) = make_float2(acc0, acc1);
    }
  }
}

// deg[v] = #edges with dst==v
__global__ __launch_bounds__(256) void k_hist(const int* __restrict__ ei,
                                              int* __restrict__ deg, int E) {
  int e = blockIdx.x * 256 + threadIdx.x;
  if (e < E) atomicAdd(&deg[ei[E + e]], 1);
}

// single-block tiled exclusive scan: off[0..N-1] = exclusive prefix, off[N] = E
__global__ __launch_bounds__(256) void k_scan(const int* __restrict__ deg,
                                              int* __restrict__ off, int N, int E) {
  __shared__ int wsum[4];
  __shared__ int carry_s;
  if (threadIdx.x == 0) carry_s = 0;
  int lane = threadIdx.x & 63, wave = threadIdx.x >> 6;
  for (int base = 0; base < N; base += 1024) {
    __syncthreads();
    int idx = base + threadIdx.x * 4;
    int4 v = make_int4(0, 0, 0, 0);
    if (idx + 3 < N) {
      v = *(const int4*)(deg + idx);
    } else {
      if (idx < N) v.x = deg[idx];
      if (idx + 1 < N) v.y = deg[idx + 1];
      if (idx + 2 < N) v.z = deg[idx + 2];
      if (idx + 3 < N) v.w = deg[idx + 3];
    }
    int s = v.x + v.y + v.z + v.w;
    int sc = s;
#pragma unroll
    for (int m = 1; m < 64; m <<= 1) {
      int o = __shfl_up(sc, m, 64);
      if (lane >= m) sc += o;
    }
    if (lane == 63) wsum[wave] = sc;
    __syncthreads();
    int wbase = 0;
    for (int w = 0; w < wave; ++w) wbase += wsum[w];
    int excl = carry_s + wbase + (sc - s);
    if (idx < N) off[idx] = excl;
    if (idx + 1 < N) off[idx + 1] = excl + v.x;
    if (idx + 2 < N) off[idx + 2] = excl + v.x + v.y;
    if (idx + 3 < N) off[idx + 3] = excl + v.x + v.y + v.z;
    __syncthreads();
    if (threadIdx.x == 0) carry_s += wsum[0] + wsum[1] + wsum[2] + wsum[3];
  }
  if (threadIdx.x == 0) off[N] = E;
}

// ssrc[off[d] + k] = src for the k-th edge (any order) with dst==d
__global__ __launch_bounds__(256) void k_place(const int* __restrict__ ei,
                                               const int* __restrict__ off,
                                               int* __restrict__ cursor,
                                               int* __restrict__ ssrc, int E) {
  int e = blockIdx.x * 256 + threadIdx.x;
  if (e >= E) return;
  int s = ei[e];
  int d = ei[E + e];
  int pos = atomicAdd(&cursor[d], 1);
  ssrc[off[d] + pos] = s;
}

// A[v] = deg(v)>0 ? max_{e->v} P[src] - P[v] + b_edge : 0   (one wave per vertex)
__global__ __launch_bounds__(256) void k_segmax(const float* __restrict__ P,
                                                const int* __restrict__ off,
                                                const int* __restrict__ ssrc,
                                                const float* __restrict__ b_edge,
                                                float* __restrict__ A, int N) {
  int wave = threadIdx.x >> 6, lane = threadIdx.x & 63;
  int v = blockIdx.x * 4 + wave;
  if (v >= N) return;
  int beg = off[v], end = off[v + 1];
  int deg = end - beg;
  float m0 = -__builtin_inff(), m1 = -__builtin_inff();
  for (int r = 0; r < deg; r += 64) {
    int cnt = min(64, deg - r);
    int sv = (lane < cnt) ? ssrc[beg + r + lane] : 0;
#pragma unroll 4
    for (int i = 0; i < cnt; ++i) {
      int s = __shfl(sv, i, 64);
      float2 p = *(const float2*)(P + (size_t)s * DOUT + lane * 2);
      m0 = fmaxf(m0, p.x);
      m1 = fmaxf(m1, p.y);
    }
  }
  float2 pv = *(const float2*)(P + (size_t)v * DOUT + lane * 2);
  float2 be = *(const float2*)(b_edge + lane * 2);
  float a0 = (deg > 0) ? (m0 - pv.x + be.x) : 0.f;
  float a1 = (deg > 0) ? (m1 - pv.y + be.y) : 0.f;
  *(float2*)(A + (size_t)v * DOUT + lane * 2) = make_float2(a0, a1);
}

// h[N,128] = relu(LN(concat(vf, A) @ W1 + b1))
__global__ __launch_bounds__(256) void k_mlp1(
    const float* __restrict__ vf, const float* __restrict__ A,
    const float* __restrict__ W1, const float* __restrict__ b1,
    const float* __restrict__ gamma, const float* __restrict__ beta,
    float* __restrict__ h, int N) {
  __shared__ float Wl[256 * DOUT];   // 128 KB
  __shared__ float rowbuf[4][256];   // 4 KB
  for (int i = threadIdx.x * 4; i < 256 * DOUT; i += 256 * 4)
    *(float4*)(&Wl[i]) = *(const float4*)(&W1[i]);
  int wave = threadIdx.x >> 6, lane = threadIdx.x & 63;
  int ntiles = (N + 3) >> 2;
  for (int tile = blockIdx.x; tile < ntiles; tile += gridDim.x) {
    int row0 = tile * 4;
    __syncthreads();
    {
      // 4 rows x 256 cols = 256 float4s, one per thread
      int r = threadIdx.x >> 6;
      int col = (threadIdx.x & 63) * 4;
      int row = row0 + r;
      float4 v = make_float4(0.f, 0.f, 0.f, 0.f);
      if (row < N) {
        if (col < DIN) v = *(const float4*)(vf + (size_t)row * DIN + col);
        else           v = *(const float4*)(A + (size_t)row * DOUT + (col - DIN));
      }
      *(float4*)(&rowbuf[r][col]) = v;
    }
    __syncthreads();
    int row = row0 + wave;
    if (row < N) {
      float acc0 = 0.f, acc1 = 0.f;
      const float* rb = rowbuf[wave];
#pragma unroll 8
      for (int i = 0; i < 256; ++i) {
        float c = rb[i];
        float2 w = *(const float2*)(&Wl[i * DOUT + lane * 2]);
        acc0 = fmaf(c, w.x, acc0);
        acc1 = fmaf(c, w.y, acc1);
      }
      float h0 = acc0 + b1[lane * 2];
      float h1 = acc1 + b1[lane * 2 + 1];
      float s = h0 + h1, sq = h0 * h0 + h1 * h1;
#pragma unroll
      for (int m_ = 32; m_ >= 1; m_ >>= 1) {
        s += __shfl_xor(s, m_, 64);
        sq += __shfl_xor(sq, m_, 64);
      }
      float mu = s * (1.f / 128.f);
      float var = sq * (1.f / 128.f) - mu * mu;
      float rs = rsqrtf(var + LN_EPS);
      float o0 = fmaxf(fmaf((h0 - mu) * rs, gamma[lane * 2], beta[lane * 2]), 0.f);
      float o1 = fmaxf(fmaf((h1 - mu) * rs, gamma[lane * 2 + 1], beta[lane * 2 + 1]), 0.f);
      *(float2*)(h + (size_t)row * DOUT + lane * 2) = make_float2(o0, o1);
    }
  }
}

// out[N,128] = h @ W2 + b2
__global__ __launch_bounds__(256) void k_mlp2(const float* __restrict__ h,
                                              const float* __restrict__ W2,
                                              const float* __restrict__ b2,
                                              float* __restrict__ out, int N) {
  __shared__ float Wl[DOUT * DOUT];  // 64 KB
  __shared__ float rowbuf[4][DOUT];
  for (int i = threadIdx.x * 4; i < DOUT * DOUT; i += 256 * 4)
    *(float4*)(&Wl[i]) = *(const float4*)(&W2[i]);
  int wave = threadIdx.x >> 6, lane = threadIdx.x & 63;
  int ntiles = (N + 3) >> 2;
  for (int tile = blockIdx.x; tile < ntiles; tile += gridDim.x) {
    int row0 = tile * 4;
    __syncthreads();
    {
      int r = threadIdx.x >> 6, i2 = threadIdx.x & 63;
      int row = row0 + r;
      float2 v = make_float2(0.f, 0.f);
      if (row < N) v = *(const float2*)(h + (size_t)row * DOUT + i2 * 2);
      *(float2*)(&rowbuf[r][i2 * 2]) = v;
    }
    __syncthreads();
    int row = row0 + wave;
    if (row < N) {
      float acc0 = b2[lane * 2];
      float acc1 = b2[lane * 2 + 1];
      const float* rb = rowbuf[wave];
#pragma unroll 8
      for (int i = 0; i < DOUT; ++i) {
        float c = rb[i];
        float2 w = *(const float2*)(&Wl[i * DOUT + lane * 2]);
        acc0 = fmaf(c, w.x, acc0);
        acc1 = fmaf(c, w.y, acc1);
      }
      *(float2*)(out + (size_t)row * DOUT + lane * 2) = make_float2(acc0, acc1);
    }
  }
}

extern "C" void kernel_launch(void* const* d_in, const int* in_sizes, int n_in,
                              void* d_out, int out_size, void* d_ws, size_t ws_size,
                              hipStream_t stream) {
  const float* vf     = (const float*)d_in[0];
  const int*   ei     = (const int*)d_in[1];
  const float* W_edge = (const float*)d_in[2];
  const float* b_edge = (const float*)d_in[3];
  const float* W1     = (const float*)d_in[4];
  const float* b1     = (const float*)d_in[5];
  const float* gamma  = (const float*)d_in[6];
  const float* beta   = (const float*)d_in[7];
  const float* W2     = (const float*)d_in[8];
  const float* b2     = (const float*)d_in[9];
  float* out = (float*)d_out;

  int N = in_sizes[0] / DIN;
  int E = in_sizes[1] / 2;

  char* ws = (char*)d_ws;
  size_t seg = (size_t)N * DOUT * sizeof(float);
  float* P = (float*)ws;               // [N,128]; reused as h after segmax
  float* A = (float*)(ws + seg);       // [N,128] agg
  int* off    = (int*)(ws + 2 * seg);          // N+1
  int* deg    = off + (N + 1);                 // N
  int* cursor = deg + N;                       // N
  int* ssrc   = cursor + N;                    // E
  float* hbuf = P;                             // alias: P dead after segmax

  int eblk = (E + 255) / 256;
  k_gemm_vf<<<2048, 256, 0, stream>>>(vf, W_edge, P, N);
  hipMemsetAsync(deg, 0, (size_t)2 * N * sizeof(int), stream);  // deg + cursor
  k_hist<<<eblk, 256, 0, stream>>>(ei, deg, E);
  k_scan<<<1, 256, 0, stream>>>(deg, off, N, E);
  k_place<<<eblk, 256, 0, stream>>>(ei, off, cursor, ssrc, E);
  k_segmax<<<(N + 3) / 4, 256, 0, stream>>>(P, off, ssrc, b_edge, A, N);
  k_mlp1<<<256, 256, 0, stream>>>(vf, A, W1, b1, gamma, beta, hbuf, N);
  k_mlp2<<<512, 256, 0, stream>>>(hbuf, W2, b2, out, N);
}

// Round 3
// 239.985 us; speedup vs baseline: 4.0179x; 2.2836x over previous
//
#include <hip/hip_runtime.h>
#include <stdint.h>

#define DIN 128
#define DOUT 128
#define LN_EPS 1e-5f

typedef __attribute__((ext_vector_type(8))) short bf16x8;
typedef __attribute__((ext_vector_type(4))) float f32x4;

__device__ __forceinline__ unsigned short f2bf(float f) {
  uint32_t u = __float_as_uint(f);
  uint32_t r = (u + 0x7fffu + ((u >> 16) & 1u)) >> 16;
  return (unsigned short)r;
}
__device__ __forceinline__ float bf2f(uint32_t lo16) {
  return __uint_as_float(lo16 << 16);
}
__device__ __forceinline__ uint32_t pack2(unsigned short a, unsigned short b) {
  return (uint32_t)a | ((uint32_t)b << 16);
}

// ---------------------------------------------------------------------------
// Weight image: pre-transposed (col-major) bf16, XOR-swizzled, exact LDS byte
// image so blocks can copy it linearly (conflict-free b128 writes).
//   [0, 32768):       We^T  [c][k] c,k<128, row stride 256 B
//   [32768, 98304):   W1^T  [c][k] c<128, k<256, row stride 512 B
//   [98304, 131072):  W2^T  [c][k] c,k<128, row stride 256 B
// swizzle: byte_in_row = (k*2) ^ ((c&7)<<4)
// ---------------------------------------------------------------------------
__global__ __launch_bounds__(256) void k_prepw(const float* __restrict__ We,
                                               const float* __restrict__ W1,
                                               const float* __restrict__ W2,
                                               char* __restrict__ img) {
  int tid = blockIdx.x * 256 + threadIdx.x;
  const int total = 128 * 128 + 256 * 128 + 128 * 128;  // 65536
  for (int i = tid; i < total; i += gridDim.x * 256) {
    int off;
    float v;
    if (i < 16384) {
      int k = i >> 7, c = i & 127;
      v = We[k * 128 + c];
      off = c * 256 + ((k * 2) ^ ((c & 7) << 4));
    } else if (i < 49152) {
      int j = i - 16384;
      int k = j >> 7, c = j & 127;
      v = W1[k * 128 + c];
      off = 32768 + c * 512 + ((k * 2) ^ ((c & 7) << 4));
    } else {
      int j = i - 49152;
      int k = j >> 7, c = j & 127;
      v = W2[k * 128 + c];
      off = 98304 + c * 256 + ((k * 2) ^ ((c & 7) << 4));
    }
    *(unsigned short*)(img + off) = f2bf(v);
  }
}

// ---------------------------------------------------------------------------
// P16[N,128] = bf16(vf @ We); also emits vf16 = bf16(vf).
// MFMA 16x16x32, BM=64, 4 waves (16 rows each).
// ---------------------------------------------------------------------------
__global__ __launch_bounds__(256) void k_gemm_vf(const float* __restrict__ vf,
                                                 const char* __restrict__ wimg,
                                                 short* __restrict__ P16,
                                                 short* __restrict__ vf16, int N) {
  __shared__ char lds[32768 + 16384];  // Wet 32K + Xs[64][256B] 16K
  char* Wet = lds;
  char* Xs = lds + 32768;
  {
    const uint4* src = (const uint4*)wimg;
    for (int i = threadIdx.x; i < 2048; i += 256) *(uint4*)(Wet + i * 16) = src[i];
  }
  int wave = threadIdx.x >> 6, lane = threadIdx.x & 63;
  int l15 = lane & 15, lq = lane >> 4;
  int ntiles = (N + 63) >> 6;
  for (int tile = blockIdx.x; tile < ntiles; tile += gridDim.x) {
    int row0 = tile << 6;
    __syncthreads();
    {  // stage X: thread t -> row r=t>>2, k-range q*32..+32 (f32 -> bf16)
      int r = threadIdx.x >> 2, q = threadIdx.x & 3;
      int row = row0 + r;
      float4 f[8];
      if (row < N) {
        const float4* s = (const float4*)(vf + (size_t)row * DIN + q * 32);
#pragma unroll
        for (int m = 0; m < 8; ++m) f[m] = s[m];
      } else {
#pragma unroll
        for (int m = 0; m < 8; ++m) f[m] = make_float4(0.f, 0.f, 0.f, 0.f);
      }
      uint32_t o[16];
#pragma unroll
      for (int m = 0; m < 8; ++m) {
        o[2 * m] = pack2(f2bf(f[m].x), f2bf(f[m].y));
        o[2 * m + 1] = pack2(f2bf(f[m].z), f2bf(f[m].w));
      }
#pragma unroll
      for (int m = 0; m < 4; ++m) {
        int kb = q * 64 + m * 16;
        *(uint4*)(Xs + r * 256 + (kb ^ ((r & 7) << 4))) = ((uint4*)o)[m];
      }
      if (row < N) {
        uint4* dst = (uint4*)(vf16 + (size_t)row * DIN + q * 32);
#pragma unroll
        for (int m = 0; m < 4; ++m) dst[m] = ((uint4*)o)[m];
      }
    }
    __syncthreads();
    int mloc = wave * 16 + l15;
    f32x4 acc[8];
#pragma unroll
    for (int n = 0; n < 8; ++n) acc[n] = (f32x4)0.f;
#pragma unroll
    for (int ks = 0; ks < 4; ++ks) {
      int kb = ks * 64 + lq * 16;
      bf16x8 a = *(const bf16x8*)(Xs + mloc * 256 + (kb ^ ((mloc & 7) << 4)));
#pragma unroll
      for (int n = 0; n < 8; ++n) {
        int c = n * 16 + l15;
        bf16x8 b = *(const bf16x8*)(Wet + c * 256 + (kb ^ ((c & 7) << 4)));
        acc[n] = __builtin_amdgcn_mfma_f32_16x16x32_bf16(a, b, acc[n], 0, 0, 0);
      }
    }
    int rbase = row0 + wave * 16 + lq * 4;
#pragma unroll
    for (int n = 0; n < 8; ++n) {
      int col = n * 16 + l15;
#pragma unroll
      for (int reg = 0; reg < 4; ++reg) {
        int row = rbase + reg;
        if (row < N) P16[(size_t)row * DOUT + col] = (short)f2bf(acc[n][reg]);
      }
    }
  }
}

__global__ __launch_bounds__(256) void k_hist(const int* __restrict__ ei,
                                              int* __restrict__ deg, int E) {
  int e = blockIdx.x * 256 + threadIdx.x;
  if (e < E) atomicAdd(&deg[ei[E + e]], 1);
}

__global__ __launch_bounds__(256) void k_scan(const int* __restrict__ deg,
                                              int* __restrict__ off, int N, int E) {
  __shared__ int wsum[4];
  __shared__ int carry_s;
  if (threadIdx.x == 0) carry_s = 0;
  int lane = threadIdx.x & 63, wave = threadIdx.x >> 6;
  for (int base = 0; base < N; base += 1024) {
    __syncthreads();
    int idx = base + threadIdx.x * 4;
    int4 v = make_int4(0, 0, 0, 0);
    if (idx + 3 < N) {
      v = *(const int4*)(deg + idx);
    } else {
      if (idx < N) v.x = deg[idx];
      if (idx + 1 < N) v.y = deg[idx + 1];
      if (idx + 2 < N) v.z = deg[idx + 2];
      if (idx + 3 < N) v.w = deg[idx + 3];
    }
    int s = v.x + v.y + v.z + v.w;
    int sc = s;
#pragma unroll
    for (int m = 1; m < 64; m <<= 1) {
      int o = __shfl_up(sc, m, 64);
      if (lane >= m) sc += o;
    }
    if (lane == 63) wsum[wave] = sc;
    __syncthreads();
    int wbase = 0;
    for (int w = 0; w < wave; ++w) wbase += wsum[w];
    int excl = carry_s + wbase + (sc - s);
    if (idx < N) off[idx] = excl;
    if (idx + 1 < N) off[idx + 1] = excl + v.x;
    if (idx + 2 < N) off[idx + 2] = excl + v.x + v.y;
    if (idx + 3 < N) off[idx + 3] = excl + v.x + v.y + v.z;
    __syncthreads();
    if (threadIdx.x == 0) carry_s += wsum[0] + wsum[1] + wsum[2] + wsum[3];
  }
  if (threadIdx.x == 0) off[N] = E;
}

__global__ __launch_bounds__(256) void k_place(const int* __restrict__ ei,
                                               const int* __restrict__ off,
                                               int* __restrict__ cursor,
                                               int* __restrict__ ssrc, int E) {
  int e = blockIdx.x * 256 + threadIdx.x;
  if (e >= E) return;
  int s = ei[e];
  int d = ei[E + e];
  int pos = atomicAdd(&cursor[d], 1);
  ssrc[off[d] + pos] = s;
}

// A16[v] = deg>0 ? bf16(max_{e->v} P[src] - P[v] + b_edge) : 0  (wave/vertex)
__global__ __launch_bounds__(256) void k_segmax(const short* __restrict__ P16,
                                                const int* __restrict__ off,
                                                const int* __restrict__ ssrc,
                                                const float* __restrict__ b_edge,
                                                short* __restrict__ A16, int N) {
  int wave = threadIdx.x >> 6, lane = threadIdx.x & 63;
  int v = blockIdx.x * 4 + wave;
  if (v >= N) return;
  int beg = off[v], end = off[v + 1];
  int deg = end - beg;
  float m0 = -__builtin_inff(), m1 = -__builtin_inff();
  for (int r = 0; r < deg; r += 64) {
    int cnt = min(64, deg - r);
    int sv = (lane < cnt) ? ssrc[beg + r + lane] : 0;
#pragma unroll 4
    for (int i = 0; i < cnt; ++i) {
      int s = __shfl(sv, i, 64);
      uint32_t p = *(const uint32_t*)(P16 + (size_t)s * DOUT + lane * 2);
      m0 = fmaxf(m0, bf2f(p & 0xffffu));
      m1 = fmaxf(m1, bf2f(p >> 16));
    }
  }
  uint32_t pv = *(const uint32_t*)(P16 + (size_t)v * DOUT + lane * 2);
  float2 be = *(const float2*)(b_edge + lane * 2);
  float a0 = (deg > 0) ? (m0 - bf2f(pv & 0xffffu) + be.x) : 0.f;
  float a1 = (deg > 0) ? (m1 - bf2f(pv >> 16) + be.y) : 0.f;
  *(uint32_t*)(A16 + (size_t)v * DOUT + lane * 2) = pack2(f2bf(a0), f2bf(a1));
}

// ---------------------------------------------------------------------------
// out = relu(LN(concat(vf16,A16) @ W1 + b1)) @ W2 + b2   (fused, MFMA)
// BM=64, 4 waves x 16 rows. LDS: W1t 64K | W2t 32K | Xs 32K | Hs 16K = 144K
// ---------------------------------------------------------------------------
__global__ __launch_bounds__(256) void k_mlp12(
    const short* __restrict__ vf16, const short* __restrict__ A16,
    const char* __restrict__ wimg, const float* __restrict__ b1,
    const float* __restrict__ gamma, const float* __restrict__ beta,
    const float* __restrict__ b2, float* __restrict__ out, int N) {
  __shared__ char lds[147456];
  char* W1t = lds;            // 65536 B, row stride 512
  char* W2t = lds + 65536;    // 32768 B, row stride 256
  char* Xs = lds + 98304;     // 64 x 512 B
  char* Hs = lds + 131072;    // 64 x 256 B
  {
    const uint4* src = (const uint4*)(wimg + 32768);  // W1t+W2t image, 96 KB
    for (int i = threadIdx.x; i < 6144; i += 256) *(uint4*)(W1t + i * 16) = src[i];
  }
  int wave = threadIdx.x >> 6, lane = threadIdx.x & 63;
  int l15 = lane & 15, lq = lane >> 4;
  float b1v[8], gv[8], bev[8], b2v[8];
#pragma unroll
  for (int n = 0; n < 8; ++n) {
    int c = n * 16 + l15;
    b1v[n] = b1[c];
    gv[n] = gamma[c];
    bev[n] = beta[c];
    b2v[n] = b2[c];
  }
  int ntiles = (N + 63) >> 6;
  for (int tile = blockIdx.x; tile < ntiles; tile += gridDim.x) {
    int row0 = tile << 6;
    __syncthreads();
    {  // stage Xs[64][256k]: thread t -> row r=t>>2, byte-range q*128..+128
      int r = threadIdx.x >> 2, q = threadIdx.x & 3;
      int row = row0 + r;
      uint4 v[8];
      if (row < N) {
        const uint4* s = (q < 2) ? (const uint4*)(vf16 + (size_t)row * DIN + q * 64)
                                 : (const uint4*)(A16 + (size_t)row * DOUT + (q - 2) * 64);
#pragma unroll
        for (int m = 0; m < 8; ++m) v[m] = s[m];
      } else {
#pragma unroll
        for (int m = 0; m < 8; ++m) v[m] = make_uint4(0, 0, 0, 0);
      }
#pragma unroll
      for (int m = 0; m < 8; ++m) {
        int kb = q * 128 + m * 16;
        *(uint4*)(Xs + r * 512 + (kb ^ ((r & 7) << 4))) = v[m];
      }
    }
    __syncthreads();
    int mloc = wave * 16 + l15;
    // GEMM1: [64,256] @ [256,128]
    f32x4 acc[8];
#pragma unroll
    for (int n = 0; n < 8; ++n) acc[n] = (f32x4)0.f;
#pragma unroll
    for (int ks = 0; ks < 8; ++ks) {
      int kb = ks * 64 + lq * 16;
      bf16x8 a = *(const bf16x8*)(Xs + mloc * 512 + (kb ^ ((mloc & 7) << 4)));
#pragma unroll
      for (int n = 0; n < 8; ++n) {
        int c = n * 16 + l15;
        bf16x8 b = *(const bf16x8*)(W1t + c * 512 + (kb ^ ((c & 7) << 4)));
        acc[n] = __builtin_amdgcn_mfma_f32_16x16x32_bf16(a, b, acc[n], 0, 0, 0);
      }
    }
    // bias + LayerNorm + relu (rows spread over quarter-wave x 4 regs)
    float h[8][4];
#pragma unroll
    for (int n = 0; n < 8; ++n)
#pragma unroll
      for (int reg = 0; reg < 4; ++reg) h[n][reg] = acc[n][reg] + b1v[n];
    float s[4], sq[4];
#pragma unroll
    for (int reg = 0; reg < 4; ++reg) {
      s[reg] = 0.f;
      sq[reg] = 0.f;
#pragma unroll
      for (int n = 0; n < 8; ++n) {
        s[reg] += h[n][reg];
        sq[reg] += h[n][reg] * h[n][reg];
      }
    }
#pragma unroll
    for (int m = 1; m < 16; m <<= 1) {
#pragma unroll
      for (int reg = 0; reg < 4; ++reg) {
        s[reg] += __shfl_xor(s[reg], m, 64);
        sq[reg] += __shfl_xor(sq[reg], m, 64);
      }
    }
#pragma unroll
    for (int reg = 0; reg < 4; ++reg) {
      float mu = s[reg] * (1.f / 128.f);
      float var = sq[reg] * (1.f / 128.f) - mu * mu;
      float rs = rsqrtf(var + LN_EPS);
      int rr = wave * 16 + lq * 4 + reg;
#pragma unroll
      for (int n = 0; n < 8; ++n) {
        float o = fmaxf(fmaf((h[n][reg] - mu) * rs, gv[n], bev[n]), 0.f);
        int c = n * 16 + l15;
        *(unsigned short*)(Hs + rr * 256 + ((c * 2) ^ ((rr & 7) << 4))) = f2bf(o);
      }
    }
    __syncthreads();
    // GEMM2: [64,128] @ [128,128]
    f32x4 acc2[8];
#pragma unroll
    for (int n = 0; n < 8; ++n) acc2[n] = (f32x4)0.f;
#pragma unroll
    for (int ks = 0; ks < 4; ++ks) {
      int kb = ks * 64 + lq * 16;
      bf16x8 a = *(const bf16x8*)(Hs + mloc * 256 + (kb ^ ((mloc & 7) << 4)));
#pragma unroll
      for (int n = 0; n < 8; ++n) {
        int c = n * 16 + l15;
        bf16x8 b = *(const bf16x8*)(W2t + c * 256 + (kb ^ ((c & 7) << 4)));
        acc2[n] = __builtin_amdgcn_mfma_f32_16x16x32_bf16(a, b, acc2[n], 0, 0, 0);
      }
    }
    int rbase = row0 + wave * 16 + lq * 4;
#pragma unroll
    for (int n = 0; n < 8; ++n) {
      int col = n * 16 + l15;
#pragma unroll
      for (int reg = 0; reg < 4; ++reg) {
        int row = rbase + reg;
        if (row < N) out[(size_t)row * DOUT + col] = acc2[n][reg] + b2v[n];
      }
    }
  }
}

extern "C" void kernel_launch(void* const* d_in, const int* in_sizes, int n_in,
                              void* d_out, int out_size, void* d_ws, size_t ws_size,
                              hipStream_t stream) {
  const float* vf     = (const float*)d_in[0];
  const int*   ei     = (const int*)d_in[1];
  const float* W_edge = (const float*)d_in[2];
  const float* b_edge = (const float*)d_in[3];
  const float* W1     = (const float*)d_in[4];
  const float* b1     = (const float*)d_in[5];
  const float* gamma  = (const float*)d_in[6];
  const float* beta   = (const float*)d_in[7];
  const float* W2     = (const float*)d_in[8];
  const float* b2     = (const float*)d_in[9];
  float* out = (float*)d_out;

  int N = in_sizes[0] / DIN;
  int E = in_sizes[1] / 2;

  char* ws = (char*)d_ws;
  size_t seg16 = (size_t)N * DOUT * sizeof(short);  // 12.8 MB
  short* P16  = (short*)ws;
  short* vf16 = (short*)(ws + seg16);
  short* A16  = (short*)(ws + 2 * seg16);
  char*  wimg = ws + 3 * seg16;                     // 131072 B
  int* off    = (int*)(ws + 3 * seg16 + 131072);    // N+1
  int* deg    = off + (N + 1);
  int* cursor = deg + N;
  int* ssrc   = cursor + N;                         // E

  int eblk = (E + 255) / 256;
  k_prepw<<<64, 256, 0, stream>>>(W_edge, W1, W2, wimg);
  k_gemm_vf<<<782, 256, 0, stream>>>(vf, wimg, P16, vf16, N);
  hipMemsetAsync(deg, 0, (size_t)2 * N * sizeof(int), stream);
  k_hist<<<eblk, 256, 0, stream>>>(ei, deg, E);
  k_scan<<<1, 256, 0, stream>>>(deg, off, N, E);
  k_place<<<eblk, 256, 0, stream>>>(ei, off, cursor, ssrc, E);
  k_segmax<<<(N + 3) / 4, 256, 0, stream>>>(P16, off, ssrc, b_edge, A16, N);
  k_mlp12<<<256, 256, 0, stream>>>(vf16, A16, wimg, b1, gamma, beta, b2, out, N);
}

// Round 4
// 226.760 us; speedup vs baseline: 4.2522x; 1.0583x over previous
//
#include <hip/hip_runtime.h>
#include <stdint.h>

#define DIN 128
#define DOUT 128
#define LN_EPS 1e-5f

typedef __attribute__((ext_vector_type(8))) short bf16x8;
typedef __attribute__((ext_vector_type(4))) float f32x4;

__device__ __forceinline__ unsigned short f2bf(float f) {
  uint32_t u = __float_as_uint(f);
  uint32_t r = (u + 0x7fffu + ((u >> 16) & 1u)) >> 16;
  return (unsigned short)r;
}
__device__ __forceinline__ float bf2f(uint32_t lo16) {
  return __uint_as_float(lo16 << 16);
}
__device__ __forceinline__ uint32_t pack2(unsigned short a, unsigned short b) {
  return (uint32_t)a | ((uint32_t)b << 16);
}

// ---------------------------------------------------------------------------
// Weight image: plain transposed bf16 (no swizzle — consumed from global):
//   [0, 32768):       We^T [c<128][k<128], row stride 256 B
//   [32768, 98304):   W1^T [c<128][k<256], row stride 512 B
//   [98304, 131072):  W2^T [c<128][k<128], row stride 256 B
// ---------------------------------------------------------------------------
__global__ __launch_bounds__(256) void k_prepw(const float* __restrict__ We,
                                               const float* __restrict__ W1,
                                               const float* __restrict__ W2,
                                               char* __restrict__ img) {
  int tid = blockIdx.x * 256 + threadIdx.x;
  const int total = 128 * 128 + 256 * 128 + 128 * 128;  // 65536
  for (int i = tid; i < total; i += gridDim.x * 256) {
    int off;
    float v;
    if (i < 16384) {
      int k = i >> 7, c = i & 127;
      v = We[k * 128 + c];
      off = c * 256 + k * 2;
    } else if (i < 49152) {
      int j = i - 16384;
      int k = j >> 7, c = j & 127;
      v = W1[k * 128 + c];
      off = 32768 + c * 512 + k * 2;
    } else {
      int j = i - 49152;
      int k = j >> 7, c = j & 127;
      v = W2[k * 128 + c];
      off = 98304 + c * 256 + k * 2;
    }
    *(unsigned short*)(img + off) = f2bf(v);
  }
}

// ---------------------------------------------------------------------------
// P16 = bf16(vf @ We), vf16 = bf16(vf). MFMA 16x16x32, BM=64, one tile/block.
// B-fragments straight from global wimg (L2-resident). LDS: Xs 16 KB.
// ---------------------------------------------------------------------------
__global__ __launch_bounds__(256) void k_gemm_vf(const float* __restrict__ vf,
                                                 const char* __restrict__ wimg,
                                                 short* __restrict__ P16,
                                                 short* __restrict__ vf16, int N) {
  __shared__ char Xs[16384];  // 64 rows x 256 B, XOR-swizzled
  int wave = threadIdx.x >> 6, lane = threadIdx.x & 63;
  int l15 = lane & 15, lq = lane >> 4;
  int row0 = blockIdx.x << 6;
  {  // stage: thread t -> row r=t>>2, k-range q*32..+32 (f32 -> bf16)
    int r = threadIdx.x >> 2, q = threadIdx.x & 3;
    int row = row0 + r;
    float4 f[8];
    if (row < N) {
      const float4* s = (const float4*)(vf + (size_t)row * DIN + q * 32);
#pragma unroll
      for (int m = 0; m < 8; ++m) f[m] = s[m];
    } else {
#pragma unroll
      for (int m = 0; m < 8; ++m) f[m] = make_float4(0.f, 0.f, 0.f, 0.f);
    }
    uint32_t o[16];
#pragma unroll
    for (int m = 0; m < 8; ++m) {
      o[2 * m] = pack2(f2bf(f[m].x), f2bf(f[m].y));
      o[2 * m + 1] = pack2(f2bf(f[m].z), f2bf(f[m].w));
    }
#pragma unroll
    for (int m = 0; m < 4; ++m) {
      int kb = q * 64 + m * 16;
      *(uint4*)(Xs + r * 256 + (kb ^ ((r & 7) << 4))) = ((uint4*)o)[m];
    }
    if (row < N) {
      uint4* dst = (uint4*)(vf16 + (size_t)row * DIN + q * 32);
#pragma unroll
      for (int m = 0; m < 4; ++m) dst[m] = ((uint4*)o)[m];
    }
  }
  __syncthreads();
  int mloc = wave * 16 + l15;
  f32x4 acc[8];
#pragma unroll
  for (int n = 0; n < 8; ++n) acc[n] = (f32x4)0.f;
#pragma unroll
  for (int ks = 0; ks < 4; ++ks) {
    int kb = ks * 64 + lq * 16;
    bf16x8 a = *(const bf16x8*)(Xs + mloc * 256 + (kb ^ ((mloc & 7) << 4)));
#pragma unroll
    for (int n = 0; n < 8; ++n) {
      int c = n * 16 + l15;
      bf16x8 b = *(const bf16x8*)(wimg + c * 256 + kb);
      acc[n] = __builtin_amdgcn_mfma_f32_16x16x32_bf16(a, b, acc[n], 0, 0, 0);
    }
  }
  int rbase = row0 + wave * 16 + lq * 4;
#pragma unroll
  for (int n = 0; n < 8; ++n) {
    int col = n * 16 + l15;
#pragma unroll
    for (int reg = 0; reg < 4; ++reg) {
      int row = rbase + reg;
      if (row < N) P16[(size_t)row * DOUT + col] = (short)f2bf(acc[n][reg]);
    }
  }
}

__global__ __launch_bounds__(256) void k_hist(const int* __restrict__ ei,
                                              int* __restrict__ deg, int E) {
  int e = blockIdx.x * 256 + threadIdx.x;
  if (e < E) atomicAdd(&deg[ei[E + e]], 1);
}

__global__ __launch_bounds__(1024) void k_scan(const int* __restrict__ deg,
                                               int* __restrict__ off, int N, int E) {
  __shared__ int wsum[16];
  __shared__ int carry_s;
  if (threadIdx.x == 0) carry_s = 0;
  int lane = threadIdx.x & 63, wave = threadIdx.x >> 6;
  for (int base = 0; base < N; base += 4096) {
    __syncthreads();
    int idx = base + threadIdx.x * 4;
    int4 v = make_int4(0, 0, 0, 0);
    if (idx + 3 < N) {
      v = *(const int4*)(deg + idx);
    } else {
      if (idx < N) v.x = deg[idx];
      if (idx + 1 < N) v.y = deg[idx + 1];
      if (idx + 2 < N) v.z = deg[idx + 2];
      if (idx + 3 < N) v.w = deg[idx + 3];
    }
    int s = v.x + v.y + v.z + v.w;
    int sc = s;
#pragma unroll
    for (int m = 1; m < 64; m <<= 1) {
      int o = __shfl_up(sc, m, 64);
      if (lane >= m) sc += o;
    }
    if (lane == 63) wsum[wave] = sc;
    __syncthreads();
    int wbase = 0;
    for (int w = 0; w < wave; ++w) wbase += wsum[w];
    int excl = carry_s + wbase + (sc - s);
    if (idx < N) off[idx] = excl;
    if (idx + 1 < N) off[idx + 1] = excl + v.x;
    if (idx + 2 < N) off[idx + 2] = excl + v.x + v.y;
    if (idx + 3 < N) off[idx + 3] = excl + v.x + v.y + v.z;
    __syncthreads();
    if (threadIdx.x == 0) {
      int t = 0;
#pragma unroll
      for (int w = 0; w < 16; ++w) t += wsum[w];
      carry_s += t;
    }
  }
  if (threadIdx.x == 0) off[N] = E;
}

__global__ __launch_bounds__(256) void k_place(const int* __restrict__ ei,
                                               const int* __restrict__ off,
                                               int* __restrict__ cursor,
                                               int* __restrict__ ssrc, int E) {
  int e = blockIdx.x * 256 + threadIdx.x;
  if (e >= E) return;
  int s = ei[e];
  int d = ei[E + e];
  int pos = atomicAdd(&cursor[d], 1);
  ssrc[off[d] + pos] = s;
}

// ---------------------------------------------------------------------------
// A16[v] = deg>0 ? bf16(max P[src] - P[v] + b_edge) : 0
// 16-lane groups (uint4 = 8 bf16/lane), 4 vertices per wave, 16 per block.
// ---------------------------------------------------------------------------
__global__ __launch_bounds__(256) void k_segmax(const short* __restrict__ P16,
                                                const int* __restrict__ off,
                                                const int* __restrict__ ssrc,
                                                const float* __restrict__ b_edge,
                                                short* __restrict__ A16, int N) {
  int lane = threadIdx.x & 63;
  int l16 = lane & 15;
  int v = blockIdx.x * 16 + (threadIdx.x >> 4);
  if (v >= N) return;
  int beg = off[v], end = off[v + 1];
  int deg = end - beg;
  float m[8];
#pragma unroll
  for (int j = 0; j < 8; ++j) m[j] = -__builtin_inff();
  for (int r = 0; r < deg; r += 16) {
    int cnt = min(16, deg - r);
    int sv = (l16 < cnt) ? ssrc[beg + r + l16] : 0;
    for (int i = 0; i < cnt; ++i) {
      int s = __shfl(sv, (lane & 48) + i, 64);
      uint4 p = *(const uint4*)(P16 + (size_t)s * DOUT + l16 * 8);
      m[0] = fmaxf(m[0], bf2f(p.x & 0xffffu));
      m[1] = fmaxf(m[1], bf2f(p.x >> 16));
      m[2] = fmaxf(m[2], bf2f(p.y & 0xffffu));
      m[3] = fmaxf(m[3], bf2f(p.y >> 16));
      m[4] = fmaxf(m[4], bf2f(p.z & 0xffffu));
      m[5] = fmaxf(m[5], bf2f(p.z >> 16));
      m[6] = fmaxf(m[6], bf2f(p.w & 0xffffu));
      m[7] = fmaxf(m[7], bf2f(p.w >> 16));
    }
  }
  uint4 pv = *(const uint4*)(P16 + (size_t)v * DOUT + l16 * 8);
  float4 be0 = *(const float4*)(b_edge + l16 * 8);
  float4 be1 = *(const float4*)(b_edge + l16 * 8 + 4);
  float pvf[8] = {bf2f(pv.x & 0xffffu), bf2f(pv.x >> 16), bf2f(pv.y & 0xffffu),
                  bf2f(pv.y >> 16),     bf2f(pv.z & 0xffffu), bf2f(pv.z >> 16),
                  bf2f(pv.w & 0xffffu), bf2f(pv.w >> 16)};
  float bev[8] = {be0.x, be0.y, be0.z, be0.w, be1.x, be1.y, be1.z, be1.w};
  uint32_t o[4];
#pragma unroll
  for (int j = 0; j < 4; ++j) {
    float a0 = (deg > 0) ? (m[2 * j] - pvf[2 * j] + bev[2 * j]) : 0.f;
    float a1 = (deg > 0) ? (m[2 * j + 1] - pvf[2 * j + 1] + bev[2 * j + 1]) : 0.f;
    o[j] = pack2(f2bf(a0), f2bf(a1));
  }
  *(uint4*)(A16 + (size_t)v * DOUT + l16 * 8) = *(uint4*)o;
}

// ---------------------------------------------------------------------------
// out = relu(LN(concat(vf16,A16) @ W1 + b1)) @ W2 + b2  (fused MFMA)
// BM=64, one tile/block. B-frags from global wimg. LDS: Xs 32K + Hs 16K.
// ---------------------------------------------------------------------------
__global__ __launch_bounds__(256) void k_mlp12(
    const short* __restrict__ vf16, const short* __restrict__ A16,
    const char* __restrict__ wimg, const float* __restrict__ b1,
    const float* __restrict__ gamma, const float* __restrict__ beta,
    const float* __restrict__ b2, float* __restrict__ out, int N) {
  __shared__ char Xs[32768];  // 64 x 512 B, swizzled
  __shared__ char Hs[16384];  // 64 x 256 B, swizzled
  const char* W1t = wimg + 32768;
  const char* W2t = wimg + 98304;
  int wave = threadIdx.x >> 6, lane = threadIdx.x & 63;
  int l15 = lane & 15, lq = lane >> 4;
  int row0 = blockIdx.x << 6;
  float b1v[8], gv[8], bev[8], b2v[8];
#pragma unroll
  for (int n = 0; n < 8; ++n) {
    int c = n * 16 + l15;
    b1v[n] = b1[c];
    gv[n] = gamma[c];
    bev[n] = beta[c];
    b2v[n] = b2[c];
  }
  {  // stage Xs: thread t -> row r=t>>2, byte-range q*128..+128
    int r = threadIdx.x >> 2, q = threadIdx.x & 3;
    int row = row0 + r;
    uint4 v[8];
    if (row < N) {
      const uint4* s = (q < 2) ? (const uint4*)(vf16 + (size_t)row * DIN + q * 64)
                               : (const uint4*)(A16 + (size_t)row * DOUT + (q - 2) * 64);
#pragma unroll
      for (int m = 0; m < 8; ++m) v[m] = s[m];
    } else {
#pragma unroll
      for (int m = 0; m < 8; ++m) v[m] = make_uint4(0, 0, 0, 0);
    }
#pragma unroll
    for (int m = 0; m < 8; ++m) {
      int kb = q * 128 + m * 16;
      *(uint4*)(Xs + r * 512 + (kb ^ ((r & 7) << 4))) = v[m];
    }
  }
  __syncthreads();
  int mloc = wave * 16 + l15;
  // GEMM1: [64,256] @ [256,128]
  f32x4 acc[8];
#pragma unroll
  for (int n = 0; n < 8; ++n) acc[n] = (f32x4)0.f;
#pragma unroll
  for (int ks = 0; ks < 8; ++ks) {
    int kb = ks * 64 + lq * 16;
    bf16x8 a = *(const bf16x8*)(Xs + mloc * 512 + (kb ^ ((mloc & 7) << 4)));
#pragma unroll
    for (int n = 0; n < 8; ++n) {
      int c = n * 16 + l15;
      bf16x8 b = *(const bf16x8*)(W1t + c * 512 + kb);
      acc[n] = __builtin_amdgcn_mfma_f32_16x16x32_bf16(a, b, acc[n], 0, 0, 0);
    }
  }
  // bias + LayerNorm + relu
  float h[8][4];
#pragma unroll
  for (int n = 0; n < 8; ++n)
#pragma unroll
    for (int reg = 0; reg < 4; ++reg) h[n][reg] = acc[n][reg] + b1v[n];
  float s[4], sq[4];
#pragma unroll
  for (int reg = 0; reg < 4; ++reg) {
    s[reg] = 0.f;
    sq[reg] = 0.f;
#pragma unroll
    for (int n = 0; n < 8; ++n) {
      s[reg] += h[n][reg];
      sq[reg] += h[n][reg] * h[n][reg];
    }
  }
#pragma unroll
  for (int m = 1; m < 16; m <<= 1) {
#pragma unroll
    for (int reg = 0; reg < 4; ++reg) {
      s[reg] += __shfl_xor(s[reg], m, 64);
      sq[reg] += __shfl_xor(sq[reg], m, 64);
    }
  }
#pragma unroll
  for (int reg = 0; reg < 4; ++reg) {
    float mu = s[reg] * (1.f / 128.f);
    float var = sq[reg] * (1.f / 128.f) - mu * mu;
    float rs = rsqrtf(var + LN_EPS);
    int rr = wave * 16 + lq * 4 + reg;
#pragma unroll
    for (int n = 0; n < 8; ++n) {
      float o = fmaxf(fmaf((h[n][reg] - mu) * rs, gv[n], bev[n]), 0.f);
      int c = n * 16 + l15;
      *(unsigned short*)(Hs + rr * 256 + ((c * 2) ^ ((rr & 7) << 4))) = f2bf(o);
    }
  }
  __syncthreads();
  // GEMM2: [64,128] @ [128,128]
  f32x4 acc2[8];
#pragma unroll
  for (int n = 0; n < 8; ++n) acc2[n] = (f32x4)0.f;
#pragma unroll
  for (int ks = 0; ks < 4; ++ks) {
    int kb = ks * 64 + lq * 16;
    bf16x8 a = *(const bf16x8*)(Hs + mloc * 256 + (kb ^ ((mloc & 7) << 4)));
#pragma unroll
    for (int n = 0; n < 8; ++n) {
      int c = n * 16 + l15;
      bf16x8 b = *(const bf16x8*)(W2t + c * 256 + kb);
      acc2[n] = __builtin_amdgcn_mfma_f32_16x16x32_bf16(a, b, acc2[n], 0, 0, 0);
    }
  }
  int rbase = row0 + wave * 16 + lq * 4;
#pragma unroll
  for (int n = 0; n < 8; ++n) {
    int col = n * 16 + l15;
#pragma unroll
    for (int reg = 0; reg < 4; ++reg) {
      int row = rbase + reg;
      if (row < N) out[(size_t)row * DOUT + col] = acc2[n][reg] + b2v[n];
    }
  }
}

extern "C" void kernel_launch(void* const* d_in, const int* in_sizes, int n_in,
                              void* d_out, int out_size, void* d_ws, size_t ws_size,
                              hipStream_t stream) {
  const float* vf     = (const float*)d_in[0];
  const int*   ei     = (const int*)d_in[1];
  const float* W_edge = (const float*)d_in[2];
  const float* b_edge = (const float*)d_in[3];
  const float* W1     = (const float*)d_in[4];
  const float* b1     = (const float*)d_in[5];
  const float* gamma  = (const float*)d_in[6];
  const float* beta   = (const float*)d_in[7];
  const float* W2     = (const float*)d_in[8];
  const float* b2     = (const float*)d_in[9];
  float* out = (float*)d_out;

  int N = in_sizes[0] / DIN;
  int E = in_sizes[1] / 2;
  int ntiles = (N + 63) / 64;

  char* ws = (char*)d_ws;
  size_t seg16 = (size_t)N * DOUT * sizeof(short);  // 12.8 MB
  short* P16  = (short*)ws;
  short* vf16 = (short*)(ws + seg16);
  short* A16  = (short*)(ws + 2 * seg16);
  char*  wimg = ws + 3 * seg16;                     // 131072 B
  int* off    = (int*)(ws + 3 * seg16 + 131072);    // N+1
  int* deg    = off + (N + 1);
  int* cursor = deg + N;
  int* ssrc   = cursor + N;                         // E

  int eblk = (E + 255) / 256;
  k_prepw<<<64, 256, 0, stream>>>(W_edge, W1, W2, wimg);
  k_gemm_vf<<<ntiles, 256, 0, stream>>>(vf, wimg, P16, vf16, N);
  hipMemsetAsync(deg, 0, (size_t)2 * N * sizeof(int), stream);
  k_hist<<<eblk, 256, 0, stream>>>(ei, deg, E);
  k_scan<<<1, 1024, 0, stream>>>(deg, off, N, E);
  k_place<<<eblk, 256, 0, stream>>>(ei, off, cursor, ssrc, E);
  k_segmax<<<(N + 15) / 16, 256, 0, stream>>>(P16, off, ssrc, b_edge, A16, N);
  k_mlp12<<<ntiles, 256, 0, stream>>>(vf16, A16, wimg, b1, gamma, beta, b2, out, N);
}

// Round 5
// 188.381 us; speedup vs baseline: 5.1185x; 1.2037x over previous
//
#include <hip/hip_runtime.h>
#include <stdint.h>

#define DIN 128
#define DOUT 128
#define LN_EPS 1e-5f

typedef __attribute__((ext_vector_type(8))) short bf16x8;
typedef __attribute__((ext_vector_type(4))) float f32x4;

__device__ __forceinline__ unsigned short f2bf(float f) {
  uint32_t u = __float_as_uint(f);
  uint32_t r = (u + 0x7fffu + ((u >> 16) & 1u)) >> 16;
  return (unsigned short)r;
}
__device__ __forceinline__ float bf2f(uint32_t lo16) {
  return __uint_as_float(lo16 << 16);
}
__device__ __forceinline__ uint32_t pack2(unsigned short a, unsigned short b) {
  return (uint32_t)a | ((uint32_t)b << 16);
}
// packed f32x2 -> bf16x2 (RNE), low = lo
__device__ __forceinline__ uint32_t cvtpk_bf16(float lo, float hi) {
  uint32_t r;
  asm volatile("v_cvt_pk_bf16_f32 %0, %1, %2" : "=v"(r) : "v"(lo), "v"(hi));
  return r;
}

// ---------------------------------------------------------------------------
// Weight image: transposed bf16, XOR-swizzled LDS byte image (linear copy in):
//   [0, 32768):       We^T [c<128][k<128], row stride 256 B
//   [32768, 98304):   W1^T [c<128][k<256], row stride 512 B
//   [98304, 131072):  W2^T [c<128][k<128], row stride 256 B
// swizzle: byte_in_row = (k*2) ^ ((c&7)<<4)
// ---------------------------------------------------------------------------
__global__ __launch_bounds__(256) void k_prepw(const float* __restrict__ We,
                                               const float* __restrict__ W1,
                                               const float* __restrict__ W2,
                                               char* __restrict__ img) {
  int tid = blockIdx.x * 256 + threadIdx.x;
  const int total = 128 * 128 + 256 * 128 + 128 * 128;  // 65536
  for (int i = tid; i < total; i += gridDim.x * 256) {
    int off;
    float v;
    if (i < 16384) {
      int k = i >> 7, c = i & 127;
      v = We[k * 128 + c];
      off = c * 256 + ((k * 2) ^ ((c & 7) << 4));
    } else if (i < 49152) {
      int j = i - 16384;
      int k = j >> 7, c = j & 127;
      v = W1[k * 128 + c];
      off = 32768 + c * 512 + ((k * 2) ^ ((c & 7) << 4));
    } else {
      int j = i - 49152;
      int k = j >> 7, c = j & 127;
      v = W2[k * 128 + c];
      off = 98304 + c * 256 + ((k * 2) ^ ((c & 7) << 4));
    }
    *(unsigned short*)(img + off) = f2bf(v);
  }
}

// ---------------------------------------------------------------------------
// P16 = bf16(vf @ We), vf16 = bf16(vf).
// BM=256 (4 waves x 4 m-tiles), We in LDS (32K), A-frags direct from global.
// ---------------------------------------------------------------------------
__global__ __launch_bounds__(256, 1) void k_gemm_vf(const float* __restrict__ vf,
                                                    const char* __restrict__ wimg,
                                                    short* __restrict__ P16,
                                                    short* __restrict__ vf16, int N) {
  __shared__ char Wet[32768];
  {
    const uint4* src = (const uint4*)wimg;
    for (int i = threadIdx.x; i < 2048; i += 256) *(uint4*)(Wet + i * 16) = src[i];
  }
  int wave = threadIdx.x >> 6, lane = threadIdx.x & 63;
  int l15 = lane & 15, lq = lane >> 4;
  int row0 = blockIdx.x * 256 + wave * 64;
  int rs[4];
#pragma unroll
  for (int m = 0; m < 4; ++m) rs[m] = min(row0 + m * 16 + l15, N - 1);

  f32x4 acc[4][8];
#pragma unroll
  for (int m = 0; m < 4; ++m)
#pragma unroll
    for (int n = 0; n < 8; ++n) acc[m][n] = (f32x4)0.f;

  // prefetch ks=0: per m, 8 f32 at float-index ks*32 + lq*8
  float4 pf0[4], pf1[4];
#pragma unroll
  for (int m = 0; m < 4; ++m) {
    const float* p = vf + (size_t)rs[m] * DIN + lq * 8;
    pf0[m] = *(const float4*)p;
    pf1[m] = *(const float4*)(p + 4);
  }
  __syncthreads();

#pragma unroll
  for (int ks = 0; ks < 4; ++ks) {
    bf16x8 afr[4];
#pragma unroll
    for (int m = 0; m < 4; ++m) {
      uint4 st;
      st.x = cvtpk_bf16(pf0[m].x, pf0[m].y);
      st.y = cvtpk_bf16(pf0[m].z, pf0[m].w);
      st.z = cvtpk_bf16(pf1[m].x, pf1[m].y);
      st.w = cvtpk_bf16(pf1[m].z, pf1[m].w);
      afr[m] = *(bf16x8*)&st;
      int row = row0 + m * 16 + l15;
      if (row < N)
        *(uint4*)(vf16 + (size_t)row * DIN + ks * 32 + lq * 8) = st;
    }
    if (ks < 3) {
#pragma unroll
      for (int m = 0; m < 4; ++m) {
        const float* p = vf + (size_t)rs[m] * DIN + (ks + 1) * 32 + lq * 8;
        pf0[m] = *(const float4*)p;
        pf1[m] = *(const float4*)(p + 4);
      }
    }
    int kb = ks * 64 + lq * 16;
#pragma unroll
    for (int n = 0; n < 8; ++n) {
      int c = n * 16 + l15;
      bf16x8 b = *(const bf16x8*)(Wet + c * 256 + (kb ^ ((c & 7) << 4)));
#pragma unroll
      for (int m = 0; m < 4; ++m)
        acc[m][n] = __builtin_amdgcn_mfma_f32_16x16x32_bf16(afr[m], b, acc[m][n], 0, 0, 0);
    }
  }
#pragma unroll
  for (int m = 0; m < 4; ++m) {
    int rbase = row0 + m * 16 + lq * 4;
#pragma unroll
    for (int n = 0; n < 8; ++n) {
      int col = n * 16 + l15;
#pragma unroll
      for (int reg = 0; reg < 4; ++reg) {
        int row = rbase + reg;
        if (row < N) P16[(size_t)row * DOUT + col] = (short)f2bf(acc[m][n][reg]);
      }
    }
  }
}

__global__ __launch_bounds__(256) void k_hist(const int* __restrict__ ei,
                                              int* __restrict__ deg, int E) {
  int e = blockIdx.x * 256 + threadIdx.x;
  if (e < E) atomicAdd(&deg[ei[E + e]], 1);
}

__global__ __launch_bounds__(1024) void k_scan(const int* __restrict__ deg,
                                               int* __restrict__ off, int N, int E) {
  __shared__ int wsum[16];
  __shared__ int carry_s;
  if (threadIdx.x == 0) carry_s = 0;
  int lane = threadIdx.x & 63, wave = threadIdx.x >> 6;
  for (int base = 0; base < N; base += 4096) {
    __syncthreads();
    int idx = base + threadIdx.x * 4;
    int4 v = make_int4(0, 0, 0, 0);
    if (idx + 3 < N) {
      v = *(const int4*)(deg + idx);
    } else {
      if (idx < N) v.x = deg[idx];
      if (idx + 1 < N) v.y = deg[idx + 1];
      if (idx + 2 < N) v.z = deg[idx + 2];
      if (idx + 3 < N) v.w = deg[idx + 3];
    }
    int s = v.x + v.y + v.z + v.w;
    int sc = s;
#pragma unroll
    for (int m = 1; m < 64; m <<= 1) {
      int o = __shfl_up(sc, m, 64);
      if (lane >= m) sc += o;
    }
    if (lane == 63) wsum[wave] = sc;
    __syncthreads();
    int wbase = 0;
    for (int w = 0; w < wave; ++w) wbase += wsum[w];
    int excl = carry_s + wbase + (sc - s);
    if (idx < N) off[idx] = excl;
    if (idx + 1 < N) off[idx + 1] = excl + v.x;
    if (idx + 2 < N) off[idx + 2] = excl + v.x + v.y;
    if (idx + 3 < N) off[idx + 3] = excl + v.x + v.y + v.z;
    __syncthreads();
    if (threadIdx.x == 0) {
      int t = 0;
#pragma unroll
      for (int w = 0; w < 16; ++w) t += wsum[w];
      carry_s += t;
    }
  }
  if (threadIdx.x == 0) off[N] = E;
}

__global__ __launch_bounds__(256) void k_place(const int* __restrict__ ei,
                                               const int* __restrict__ off,
                                               int* __restrict__ cursor,
                                               int* __restrict__ ssrc, int E) {
  int e = blockIdx.x * 256 + threadIdx.x;
  if (e >= E) return;
  int s = ei[e];
  int d = ei[E + e];
  int pos = atomicAdd(&cursor[d], 1);
  ssrc[off[d] + pos] = s;
}

// A16[v] = deg>0 ? bf16(max P[src] - P[v] + b_edge) : 0
// 16-lane groups (uint4 = 8 bf16/lane), 4 vertices per wave.
__global__ __launch_bounds__(256) void k_segmax(const short* __restrict__ P16,
                                                const int* __restrict__ off,
                                                const int* __restrict__ ssrc,
                                                const float* __restrict__ b_edge,
                                                short* __restrict__ A16, int N) {
  int lane = threadIdx.x & 63;
  int l16 = lane & 15;
  int v = blockIdx.x * 16 + (threadIdx.x >> 4);
  if (v >= N) return;
  int beg = off[v], end = off[v + 1];
  int deg = end - beg;
  float m[8];
#pragma unroll
  for (int j = 0; j < 8; ++j) m[j] = -__builtin_inff();
  for (int r = 0; r < deg; r += 16) {
    int cnt = min(16, deg - r);
    int sv = (l16 < cnt) ? ssrc[beg + r + l16] : 0;
    for (int i = 0; i < cnt; ++i) {
      int s = __shfl(sv, (lane & 48) + i, 64);
      uint4 p = *(const uint4*)(P16 + (size_t)s * DOUT + l16 * 8);
      m[0] = fmaxf(m[0], bf2f(p.x & 0xffffu));
      m[1] = fmaxf(m[1], bf2f(p.x >> 16));
      m[2] = fmaxf(m[2], bf2f(p.y & 0xffffu));
      m[3] = fmaxf(m[3], bf2f(p.y >> 16));
      m[4] = fmaxf(m[4], bf2f(p.z & 0xffffu));
      m[5] = fmaxf(m[5], bf2f(p.z >> 16));
      m[6] = fmaxf(m[6], bf2f(p.w & 0xffffu));
      m[7] = fmaxf(m[7], bf2f(p.w >> 16));
    }
  }
  uint4 pv = *(const uint4*)(P16 + (size_t)v * DOUT + l16 * 8);
  float4 be0 = *(const float4*)(b_edge + l16 * 8);
  float4 be1 = *(const float4*)(b_edge + l16 * 8 + 4);
  float pvf[8] = {bf2f(pv.x & 0xffffu), bf2f(pv.x >> 16), bf2f(pv.y & 0xffffu),
                  bf2f(pv.y >> 16),     bf2f(pv.z & 0xffffu), bf2f(pv.z >> 16),
                  bf2f(pv.w & 0xffffu), bf2f(pv.w >> 16)};
  float bev[8] = {be0.x, be0.y, be0.z, be0.w, be1.x, be1.y, be1.z, be1.w};
  uint32_t o[4];
#pragma unroll
  for (int j = 0; j < 4; ++j) {
    float a0 = (deg > 0) ? (m[2 * j] - pvf[2 * j] + bev[2 * j]) : 0.f;
    float a1 = (deg > 0) ? (m[2 * j + 1] - pvf[2 * j + 1] + bev[2 * j + 1]) : 0.f;
    o[j] = pack2(f2bf(a0), f2bf(a1));
  }
  *(uint4*)(A16 + (size_t)v * DOUT + l16 * 8) = *(uint4*)o;
}

// ---------------------------------------------------------------------------
// out = relu(LN(concat(vf16,A16) @ W1 + b1)) @ W2 + b2
// BM=256 (4 waves x 4 m-tiles). LDS: W1t 64K (aliased by Hs after GEMM1) +
// W2t 32K = 96K. A-frags direct from global.
// ---------------------------------------------------------------------------
__global__ __launch_bounds__(256, 1) void k_mlp12(
    const short* __restrict__ vf16, const short* __restrict__ A16,
    const char* __restrict__ wimg, const float* __restrict__ b1,
    const float* __restrict__ gamma, const float* __restrict__ beta,
    const float* __restrict__ b2, float* __restrict__ out, int N) {
  __shared__ char lds[98304];
  char* W1t = lds;          // 64K; reused as Hs (256 rows x 256 B) after GEMM1
  char* W2t = lds + 65536;  // 32K
  {
    const uint4* src = (const uint4*)(wimg + 32768);
    for (int i = threadIdx.x; i < 6144; i += 256) *(uint4*)(lds + i * 16) = src[i];
  }
  int wave = threadIdx.x >> 6, lane = threadIdx.x & 63;
  int l15 = lane & 15, lq = lane >> 4;
  int row0 = blockIdx.x * 256 + wave * 64;
  int rs[4];
#pragma unroll
  for (int m = 0; m < 4; ++m) rs[m] = min(row0 + m * 16 + l15, N - 1);
  float b1v[8], gv[8], bev[8], b2v[8];
#pragma unroll
  for (int n = 0; n < 8; ++n) {
    int c = n * 16 + l15;
    b1v[n] = b1[c];
    gv[n] = gamma[c];
    bev[n] = beta[c];
    b2v[n] = b2[c];
  }
  f32x4 acc[4][8];
#pragma unroll
  for (int m = 0; m < 4; ++m)
#pragma unroll
    for (int n = 0; n < 8; ++n) acc[m][n] = (f32x4)0.f;

  uint4 pa[4];
#pragma unroll
  for (int m = 0; m < 4; ++m)
    pa[m] = *(const uint4*)(vf16 + (size_t)rs[m] * DIN + lq * 8);
  __syncthreads();

  // GEMM1: X = concat(vf16, A16) [256 k], W1t in LDS
#pragma unroll
  for (int ks = 0; ks < 8; ++ks) {
    bf16x8 afr[4];
#pragma unroll
    for (int m = 0; m < 4; ++m) afr[m] = *(bf16x8*)&pa[m];
    if (ks < 7) {
      int ks1 = ks + 1;
      const short* srcb = (ks1 < 4) ? vf16 : A16;
      int chunk = (ks1 < 4) ? ks1 : ks1 - 4;
#pragma unroll
      for (int m = 0; m < 4; ++m)
        pa[m] = *(const uint4*)(srcb + (size_t)rs[m] * DIN + chunk * 32 + lq * 8);
    }
    int kb = ks * 64 + lq * 16;
#pragma unroll
    for (int n = 0; n < 8; ++n) {
      int c = n * 16 + l15;
      bf16x8 b = *(const bf16x8*)(W1t + c * 512 + (kb ^ ((c & 7) << 4)));
#pragma unroll
      for (int m = 0; m < 4; ++m)
        acc[m][n] = __builtin_amdgcn_mfma_f32_16x16x32_bf16(afr[m], b, acc[m][n], 0, 0, 0);
    }
  }
  __syncthreads();  // all W1t reads complete before Hs overwrites

  // bias + LayerNorm + relu -> Hs (aliases W1t)
#pragma unroll
  for (int m = 0; m < 4; ++m) {
#pragma unroll
    for (int n = 0; n < 8; ++n)
#pragma unroll
      for (int reg = 0; reg < 4; ++reg) acc[m][n][reg] += b1v[n];
    float s[4], sq[4];
#pragma unroll
    for (int reg = 0; reg < 4; ++reg) {
      s[reg] = 0.f;
      sq[reg] = 0.f;
#pragma unroll
      for (int n = 0; n < 8; ++n) {
        float h = acc[m][n][reg];
        s[reg] += h;
        sq[reg] += h * h;
      }
    }
#pragma unroll
    for (int mm = 1; mm < 16; mm <<= 1) {
#pragma unroll
      for (int reg = 0; reg < 4; ++reg) {
        s[reg] += __shfl_xor(s[reg], mm, 64);
        sq[reg] += __shfl_xor(sq[reg], mm, 64);
      }
    }
#pragma unroll
    for (int reg = 0; reg < 4; ++reg) {
      float mu = s[reg] * (1.f / 128.f);
      float var = sq[reg] * (1.f / 128.f) - mu * mu;
      float rsn = rsqrtf(var + LN_EPS);
      int rr = wave * 64 + m * 16 + lq * 4 + reg;  // local row in block
#pragma unroll
      for (int n = 0; n < 8; ++n) {
        float o = fmaxf(fmaf((acc[m][n][reg] - mu) * rsn, gv[n], bev[n]), 0.f);
        int c = n * 16 + l15;
        *(unsigned short*)(W1t + rr * 256 + ((c * 2) ^ ((rr & 7) << 4))) = f2bf(o);
      }
    }
  }
  __syncthreads();

  // GEMM2: Hs @ W2t
  f32x4 acc2[4][8];
#pragma unroll
  for (int m = 0; m < 4; ++m)
#pragma unroll
    for (int n = 0; n < 8; ++n) acc2[m][n] = (f32x4)0.f;
#pragma unroll
  for (int ks = 0; ks < 4; ++ks) {
    int kb = ks * 64 + lq * 16;
    bf16x8 a2[4];
#pragma unroll
    for (int m = 0; m < 4; ++m) {
      int rr = wave * 64 + m * 16 + l15;
      a2[m] = *(const bf16x8*)(W1t + rr * 256 + (kb ^ ((rr & 7) << 4)));
    }
#pragma unroll
    for (int n = 0; n < 8; ++n) {
      int c = n * 16 + l15;
      bf16x8 b = *(const bf16x8*)(W2t + c * 256 + (kb ^ ((c & 7) << 4)));
#pragma unroll
      for (int m = 0; m < 4; ++m)
        acc2[m][n] = __builtin_amdgcn_mfma_f32_16x16x32_bf16(a2[m], b, acc2[m][n], 0, 0, 0);
    }
  }
#pragma unroll
  for (int m = 0; m < 4; ++m) {
    int rbase = row0 + m * 16 + lq * 4;
#pragma unroll
    for (int n = 0; n < 8; ++n) {
      int col = n * 16 + l15;
#pragma unroll
      for (int reg = 0; reg < 4; ++reg) {
        int row = rbase + reg;
        if (row < N) out[(size_t)row * DOUT + col] = acc2[m][n][reg] + b2v[n];
      }
    }
  }
}

extern "C" void kernel_launch(void* const* d_in, const int* in_sizes, int n_in,
                              void* d_out, int out_size, void* d_ws, size_t ws_size,
                              hipStream_t stream) {
  const float* vf     = (const float*)d_in[0];
  const int*   ei     = (const int*)d_in[1];
  const float* W_edge = (const float*)d_in[2];
  const float* b_edge = (const float*)d_in[3];
  const float* W1     = (const float*)d_in[4];
  const float* b1     = (const float*)d_in[5];
  const float* gamma  = (const float*)d_in[6];
  const float* beta   = (const float*)d_in[7];
  const float* W2     = (const float*)d_in[8];
  const float* b2     = (const float*)d_in[9];
  float* out = (float*)d_out;

  int N = in_sizes[0] / DIN;
  int E = in_sizes[1] / 2;
  int nblk = (N + 255) / 256;

  char* ws = (char*)d_ws;
  size_t seg16 = (size_t)N * DOUT * sizeof(short);  // 12.8 MB
  short* P16  = (short*)ws;
  short* vf16 = (short*)(ws + seg16);
  short* A16  = (short*)(ws + 2 * seg16);
  char*  wimg = ws + 3 * seg16;                     // 131072 B
  int* off    = (int*)(ws + 3 * seg16 + 131072);    // N+1
  int* deg    = off + (N + 1);
  int* cursor = deg + N;
  int* ssrc   = cursor + N;                         // E

  int eblk = (E + 255) / 256;
  k_prepw<<<64, 256, 0, stream>>>(W_edge, W1, W2, wimg);
  hipMemsetAsync(deg, 0, (size_t)2 * N * sizeof(int), stream);
  k_hist<<<eblk, 256, 0, stream>>>(ei, deg, E);
  k_scan<<<1, 1024, 0, stream>>>(deg, off, N, E);
  k_gemm_vf<<<nblk, 256, 0, stream>>>(vf, wimg, P16, vf16, N);
  k_place<<<eblk, 256, 0, stream>>>(ei, off, cursor, ssrc, E);
  k_segmax<<<(N + 15) / 16, 256, 0, stream>>>(P16, off, ssrc, b_edge, A16, N);
  k_mlp12<<<nblk, 256, 0, stream>>>(vf16, A16, wimg, b1, gamma, beta, b2, out, N);
}

// Round 6
// 150.055 us; speedup vs baseline: 6.4258x; 1.2554x over previous
//
#include <hip/hip_runtime.h>
#include <stdint.h>

#define DIN 128
#define DOUT 128
#define LN_EPS 1e-5f

typedef __attribute__((ext_vector_type(8))) short bf16x8;
typedef __attribute__((ext_vector_type(4))) float f32x4;

__device__ __forceinline__ unsigned short f2bf(float f) {
  uint32_t u = __float_as_uint(f);
  uint32_t r = (u + 0x7fffu + ((u >> 16) & 1u)) >> 16;
  return (unsigned short)r;
}
__device__ __forceinline__ float bf2f(uint32_t lo16) {
  return __uint_as_float(lo16 << 16);
}
__device__ __forceinline__ uint32_t pack2(unsigned short a, unsigned short b) {
  return (uint32_t)a | ((uint32_t)b << 16);
}
// packed f32x2 -> bf16x2 (RNE), low = lo
__device__ __forceinline__ uint32_t cvtpk_bf16(float lo, float hi) {
  uint32_t r;
  asm volatile("v_cvt_pk_bf16_f32 %0, %1, %2" : "=v"(r) : "v"(lo), "v"(hi));
  return r;
}

// ---------------------------------------------------------------------------
// Weight image: transposed bf16, XOR-swizzled LDS byte image (linear copy in):
//   [0, 32768):       We^T [c<128][k<128], row stride 256 B
//   [32768, 98304):   W1^T [c<128][k<256], row stride 512 B
//   [98304, 131072):  W2^T [c<128][k<128], row stride 256 B
// swizzle: byte_in_row = (k*2) ^ ((c&7)<<4)
// ---------------------------------------------------------------------------
__global__ __launch_bounds__(256) void k_prepw(const float* __restrict__ We,
                                               const float* __restrict__ W1,
                                               const float* __restrict__ W2,
                                               char* __restrict__ img) {
  int tid = blockIdx.x * 256 + threadIdx.x;
  const int total = 128 * 128 + 256 * 128 + 128 * 128;  // 65536
  for (int i = tid; i < total; i += gridDim.x * 256) {
    int off;
    float v;
    if (i < 16384) {
      int k = i >> 7, c = i & 127;
      v = We[k * 128 + c];
      off = c * 256 + ((k * 2) ^ ((c & 7) << 4));
    } else if (i < 49152) {
      int j = i - 16384;
      int k = j >> 7, c = j & 127;
      v = W1[k * 128 + c];
      off = 32768 + c * 512 + ((k * 2) ^ ((c & 7) << 4));
    } else {
      int j = i - 49152;
      int k = j >> 7, c = j & 127;
      v = W2[k * 128 + c];
      off = 98304 + c * 256 + ((k * 2) ^ ((c & 7) << 4));
    }
    *(unsigned short*)(img + off) = f2bf(v);
  }
}

// ---------------------------------------------------------------------------
// FAT kernel: blocks < nblk -> P16 = bf16(vf @ We), vf16 = bf16(vf)
//             blocks >= nblk -> hist: rank[e] = atomicAdd(&deg[dst],1)
// GEMM part: BM=256 (4 waves x 4 m-tiles), We in LDS, A-frags from global.
// ---------------------------------------------------------------------------
__global__ __launch_bounds__(256, 1) void k_gemm_hist(
    const float* __restrict__ vf, const char* __restrict__ wimg,
    short* __restrict__ P16, short* __restrict__ vf16, int N,
    const int* __restrict__ ei, int* __restrict__ deg,
    int* __restrict__ rank, int E, int nblk) {
  __shared__ char Wet[32768];
  if (blockIdx.x >= nblk) {  // ---- histogram + rank ----
    int nb = gridDim.x - nblk;
    for (int e = (blockIdx.x - nblk) * 256 + threadIdx.x; e < E; e += nb * 256) {
      int d = ei[E + e];
      rank[e] = atomicAdd(&deg[d], 1);
    }
    return;
  }
  // ---- GEMM ----
  {
    const uint4* src = (const uint4*)wimg;
    for (int i = threadIdx.x; i < 2048; i += 256) *(uint4*)(Wet + i * 16) = src[i];
  }
  int wave = threadIdx.x >> 6, lane = threadIdx.x & 63;
  int l15 = lane & 15, lq = lane >> 4;
  int row0 = blockIdx.x * 256 + wave * 64;
  int rs[4];
#pragma unroll
  for (int m = 0; m < 4; ++m) rs[m] = min(row0 + m * 16 + l15, N - 1);

  f32x4 acc[4][8];
#pragma unroll
  for (int m = 0; m < 4; ++m)
#pragma unroll
    for (int n = 0; n < 8; ++n) acc[m][n] = (f32x4)0.f;

  float4 pf0[4], pf1[4];
#pragma unroll
  for (int m = 0; m < 4; ++m) {
    const float* p = vf + (size_t)rs[m] * DIN + lq * 8;
    pf0[m] = *(const float4*)p;
    pf1[m] = *(const float4*)(p + 4);
  }
  __syncthreads();

#pragma unroll
  for (int ks = 0; ks < 4; ++ks) {
    bf16x8 afr[4];
#pragma unroll
    for (int m = 0; m < 4; ++m) {
      uint4 st;
      st.x = cvtpk_bf16(pf0[m].x, pf0[m].y);
      st.y = cvtpk_bf16(pf0[m].z, pf0[m].w);
      st.z = cvtpk_bf16(pf1[m].x, pf1[m].y);
      st.w = cvtpk_bf16(pf1[m].z, pf1[m].w);
      afr[m] = *(bf16x8*)&st;
      int row = row0 + m * 16 + l15;
      if (row < N)
        *(uint4*)(vf16 + (size_t)row * DIN + ks * 32 + lq * 8) = st;
    }
    if (ks < 3) {
#pragma unroll
      for (int m = 0; m < 4; ++m) {
        const float* p = vf + (size_t)rs[m] * DIN + (ks + 1) * 32 + lq * 8;
        pf0[m] = *(const float4*)p;
        pf1[m] = *(const float4*)(p + 4);
      }
    }
    int kb = ks * 64 + lq * 16;
#pragma unroll
    for (int n = 0; n < 8; ++n) {
      int c = n * 16 + l15;
      bf16x8 b = *(const bf16x8*)(Wet + c * 256 + (kb ^ ((c & 7) << 4)));
#pragma unroll
      for (int m = 0; m < 4; ++m)
        acc[m][n] = __builtin_amdgcn_mfma_f32_16x16x32_bf16(afr[m], b, acc[m][n], 0, 0, 0);
    }
  }
#pragma unroll
  for (int m = 0; m < 4; ++m) {
    int rbase = row0 + m * 16 + lq * 4;
#pragma unroll
    for (int n = 0; n < 8; ++n) {
      int col = n * 16 + l15;
#pragma unroll
      for (int reg = 0; reg < 4; ++reg) {
        int row = rbase + reg;
        if (row < N) P16[(size_t)row * DOUT + col] = (short)f2bf(acc[m][n][reg]);
      }
    }
  }
}

__global__ __launch_bounds__(1024) void k_scan(const int* __restrict__ deg,
                                               int* __restrict__ off, int N, int E) {
  __shared__ int wsum[16];
  __shared__ int carry_s;
  if (threadIdx.x == 0) carry_s = 0;
  int lane = threadIdx.x & 63, wave = threadIdx.x >> 6;
  for (int base = 0; base < N; base += 4096) {
    __syncthreads();
    int idx = base + threadIdx.x * 4;
    int4 v = make_int4(0, 0, 0, 0);
    if (idx + 3 < N) {
      v = *(const int4*)(deg + idx);
    } else {
      if (idx < N) v.x = deg[idx];
      if (idx + 1 < N) v.y = deg[idx + 1];
      if (idx + 2 < N) v.z = deg[idx + 2];
      if (idx + 3 < N) v.w = deg[idx + 3];
    }
    int s = v.x + v.y + v.z + v.w;
    int sc = s;
#pragma unroll
    for (int m = 1; m < 64; m <<= 1) {
      int o = __shfl_up(sc, m, 64);
      if (lane >= m) sc += o;
    }
    if (lane == 63) wsum[wave] = sc;
    __syncthreads();
    int wbase = 0;
    for (int w = 0; w < wave; ++w) wbase += wsum[w];
    int excl = carry_s + wbase + (sc - s);
    if (idx < N) off[idx] = excl;
    if (idx + 1 < N) off[idx + 1] = excl + v.x;
    if (idx + 2 < N) off[idx + 2] = excl + v.x + v.y;
    if (idx + 3 < N) off[idx + 3] = excl + v.x + v.y + v.z;
    __syncthreads();
    if (threadIdx.x == 0) {
      int t = 0;
#pragma unroll
      for (int w = 0; w < 16; ++w) t += wsum[w];
      carry_s += t;
    }
  }
  if (threadIdx.x == 0) off[N] = E;
}

// ssrc[off[d] + rank[e]] = src  — no atomics (rank precomputed in hist)
__global__ __launch_bounds__(256) void k_place(const int* __restrict__ ei,
                                               const int* __restrict__ off,
                                               const int* __restrict__ rank,
                                               int* __restrict__ ssrc, int E) {
  int e = blockIdx.x * 256 + threadIdx.x;
  if (e >= E) return;
  int s = ei[e];
  int d = ei[E + e];
  ssrc[off[d] + rank[e]] = s;
}

// A16[v] = deg>0 ? bf16(max P[src] - P[v] + b_edge) : 0
// 16-lane groups (uint4 = 8 bf16/lane), 4 vertices per wave.
__global__ __launch_bounds__(256) void k_segmax(const short* __restrict__ P16,
                                                const int* __restrict__ off,
                                                const int* __restrict__ ssrc,
                                                const float* __restrict__ b_edge,
                                                short* __restrict__ A16, int N) {
  int lane = threadIdx.x & 63;
  int l16 = lane & 15;
  int v = blockIdx.x * 16 + (threadIdx.x >> 4);
  if (v >= N) return;
  int beg = off[v], end = off[v + 1];
  int deg = end - beg;
  float m[8];
#pragma unroll
  for (int j = 0; j < 8; ++j) m[j] = -__builtin_inff();
  for (int r = 0; r < deg; r += 16) {
    int cnt = min(16, deg - r);
    int sv = (l16 < cnt) ? ssrc[beg + r + l16] : 0;
    for (int i = 0; i < cnt; ++i) {
      int s = __shfl(sv, (lane & 48) + i, 64);
      uint4 p = *(const uint4*)(P16 + (size_t)s * DOUT + l16 * 8);
      m[0] = fmaxf(m[0], bf2f(p.x & 0xffffu));
      m[1] = fmaxf(m[1], bf2f(p.x >> 16));
      m[2] = fmaxf(m[2], bf2f(p.y & 0xffffu));
      m[3] = fmaxf(m[3], bf2f(p.y >> 16));
      m[4] = fmaxf(m[4], bf2f(p.z & 0xffffu));
      m[5] = fmaxf(m[5], bf2f(p.z >> 16));
      m[6] = fmaxf(m[6], bf2f(p.w & 0xffffu));
      m[7] = fmaxf(m[7], bf2f(p.w >> 16));
    }
  }
  uint4 pv = *(const uint4*)(P16 + (size_t)v * DOUT + l16 * 8);
  float4 be0 = *(const float4*)(b_edge + l16 * 8);
  float4 be1 = *(const float4*)(b_edge + l16 * 8 + 4);
  float pvf[8] = {bf2f(pv.x & 0xffffu), bf2f(pv.x >> 16), bf2f(pv.y & 0xffffu),
                  bf2f(pv.y >> 16),     bf2f(pv.z & 0xffffu), bf2f(pv.z >> 16),
                  bf2f(pv.w & 0xffffu), bf2f(pv.w >> 16)};
  float bev[8] = {be0.x, be0.y, be0.z, be0.w, be1.x, be1.y, be1.z, be1.w};
  uint32_t o[4];
#pragma unroll
  for (int j = 0; j < 4; ++j) {
    float a0 = (deg > 0) ? (m[2 * j] - pvf[2 * j] + bev[2 * j]) : 0.f;
    float a1 = (deg > 0) ? (m[2 * j + 1] - pvf[2 * j + 1] + bev[2 * j + 1]) : 0.f;
    o[j] = pack2(f2bf(a0), f2bf(a1));
  }
  *(uint4*)(A16 + (size_t)v * DOUT + l16 * 8) = *(uint4*)o;
}

// ---------------------------------------------------------------------------
// out = relu(LN(concat(vf16,A16) @ W1 + b1)) @ W2 + b2
// BM=256 (4 waves x 4 m-tiles). LDS: W1t 64K (aliased by Hs after GEMM1) +
// W2t 32K = 96K. A-frags direct from global.
// ---------------------------------------------------------------------------
__global__ __launch_bounds__(256, 1) void k_mlp12(
    const short* __restrict__ vf16, const short* __restrict__ A16,
    const char* __restrict__ wimg, const float* __restrict__ b1,
    const float* __restrict__ gamma, const float* __restrict__ beta,
    const float* __restrict__ b2, float* __restrict__ out, int N) {
  __shared__ char lds[98304];
  char* W1t = lds;          // 64K; reused as Hs (256 rows x 256 B) after GEMM1
  char* W2t = lds + 65536;  // 32K
  {
    const uint4* src = (const uint4*)(wimg + 32768);
    for (int i = threadIdx.x; i < 6144; i += 256) *(uint4*)(lds + i * 16) = src[i];
  }
  int wave = threadIdx.x >> 6, lane = threadIdx.x & 63;
  int l15 = lane & 15, lq = lane >> 4;
  int row0 = blockIdx.x * 256 + wave * 64;
  int rs[4];
#pragma unroll
  for (int m = 0; m < 4; ++m) rs[m] = min(row0 + m * 16 + l15, N - 1);
  float b1v[8], gv[8], bev[8], b2v[8];
#pragma unroll
  for (int n = 0; n < 8; ++n) {
    int c = n * 16 + l15;
    b1v[n] = b1[c];
    gv[n] = gamma[c];
    bev[n] = beta[c];
    b2v[n] = b2[c];
  }
  f32x4 acc[4][8];
#pragma unroll
  for (int m = 0; m < 4; ++m)
#pragma unroll
    for (int n = 0; n < 8; ++n) acc[m][n] = (f32x4)0.f;

  uint4 pa[4];
#pragma unroll
  for (int m = 0; m < 4; ++m)
    pa[m] = *(const uint4*)(vf16 + (size_t)rs[m] * DIN + lq * 8);
  __syncthreads();

  // GEMM1: X = concat(vf16, A16) [256 k], W1t in LDS
#pragma unroll
  for (int ks = 0; ks < 8; ++ks) {
    bf16x8 afr[4];
#pragma unroll
    for (int m = 0; m < 4; ++m) afr[m] = *(bf16x8*)&pa[m];
    if (ks < 7) {
      int ks1 = ks + 1;
      const short* srcb = (ks1 < 4) ? vf16 : A16;
      int chunk = (ks1 < 4) ? ks1 : ks1 - 4;
#pragma unroll
      for (int m = 0; m < 4; ++m)
        pa[m] = *(const uint4*)(srcb + (size_t)rs[m] * DIN + chunk * 32 + lq * 8);
    }
    int kb = ks * 64 + lq * 16;
#pragma unroll
    for (int n = 0; n < 8; ++n) {
      int c = n * 16 + l15;
      bf16x8 b = *(const bf16x8*)(W1t + c * 512 + (kb ^ ((c & 7) << 4)));
#pragma unroll
      for (int m = 0; m < 4; ++m)
        acc[m][n] = __builtin_amdgcn_mfma_f32_16x16x32_bf16(afr[m], b, acc[m][n], 0, 0, 0);
    }
  }
  __syncthreads();  // all W1t reads complete before Hs overwrites

  // bias + LayerNorm + relu -> Hs (aliases W1t)
#pragma unroll
  for (int m = 0; m < 4; ++m) {
#pragma unroll
    for (int n = 0; n < 8; ++n)
#pragma unroll
      for (int reg = 0; reg < 4; ++reg) acc[m][n][reg] += b1v[n];
    float s[4], sq[4];
#pragma unroll
    for (int reg = 0; reg < 4; ++reg) {
      s[reg] = 0.f;
      sq[reg] = 0.f;
#pragma unroll
      for (int n = 0; n < 8; ++n) {
        float h = acc[m][n][reg];
        s[reg] += h;
        sq[reg] += h * h;
      }
    }
#pragma unroll
    for (int mm = 1; mm < 16; mm <<= 1) {
#pragma unroll
      for (int reg = 0; reg < 4; ++reg) {
        s[reg] += __shfl_xor(s[reg], mm, 64);
        sq[reg] += __shfl_xor(sq[reg], mm, 64);
      }
    }
#pragma unroll
    for (int reg = 0; reg < 4; ++reg) {
      float mu = s[reg] * (1.f / 128.f);
      float var = sq[reg] * (1.f / 128.f) - mu * mu;
      float rsn = rsqrtf(var + LN_EPS);
      int rr = wave * 64 + m * 16 + lq * 4 + reg;  // local row in block
#pragma unroll
      for (int n = 0; n < 8; ++n) {
        float o = fmaxf(fmaf((acc[m][n][reg] - mu) * rsn, gv[n], bev[n]), 0.f);
        int c = n * 16 + l15;
        *(unsigned short*)(W1t + rr * 256 + ((c * 2) ^ ((rr & 7) << 4))) = f2bf(o);
      }
    }
  }
  __syncthreads();

  // GEMM2: Hs @ W2t
  f32x4 acc2[4][8];
#pragma unroll
  for (int m = 0; m < 4; ++m)
#pragma unroll
    for (int n = 0; n < 8; ++n) acc2[m][n] = (f32x4)0.f;
#pragma unroll
  for (int ks = 0; ks < 4; ++ks) {
    int kb = ks * 64 + lq * 16;
    bf16x8 a2[4];
#pragma unroll
    for (int m = 0; m < 4; ++m) {
      int rr = wave * 64 + m * 16 + l15;
      a2[m] = *(const bf16x8*)(W1t + rr * 256 + (kb ^ ((rr & 7) << 4)));
    }
#pragma unroll
    for (int n = 0; n < 8; ++n) {
      int c = n * 16 + l15;
      bf16x8 b = *(const bf16x8*)(W2t + c * 256 + (kb ^ ((c & 7) << 4)));
#pragma unroll
      for (int m = 0; m < 4; ++m)
        acc2[m][n] = __builtin_amdgcn_mfma_f32_16x16x32_bf16(a2[m], b, acc2[m][n], 0, 0, 0);
    }
  }
#pragma unroll
  for (int m = 0; m < 4; ++m) {
    int rbase = row0 + m * 16 + lq * 4;
#pragma unroll
    for (int n = 0; n < 8; ++n) {
      int col = n * 16 + l15;
#pragma unroll
      for (int reg = 0; reg < 4; ++reg) {
        int row = rbase + reg;
        if (row < N) out[(size_t)row * DOUT + col] = acc2[m][n][reg] + b2v[n];
      }
    }
  }
}

extern "C" void kernel_launch(void* const* d_in, const int* in_sizes, int n_in,
                              void* d_out, int out_size, void* d_ws, size_t ws_size,
                              hipStream_t stream) {
  const float* vf     = (const float*)d_in[0];
  const int*   ei     = (const int*)d_in[1];
  const float* W_edge = (const float*)d_in[2];
  const float* b_edge = (const float*)d_in[3];
  const float* W1     = (const float*)d_in[4];
  const float* b1     = (const float*)d_in[5];
  const float* gamma  = (const float*)d_in[6];
  const float* beta   = (const float*)d_in[7];
  const float* W2     = (const float*)d_in[8];
  const float* b2     = (const float*)d_in[9];
  float* out = (float*)d_out;

  int N = in_sizes[0] / DIN;
  int E = in_sizes[1] / 2;
  int nblk = (N + 255) / 256;

  char* ws = (char*)d_ws;
  size_t seg16 = (size_t)N * DOUT * sizeof(short);  // 12.8 MB
  short* P16  = (short*)ws;
  short* vf16 = (short*)(ws + seg16);
  short* A16  = (short*)(ws + 2 * seg16);
  char*  wimg = ws + 3 * seg16;                     // 131072 B
  int* off    = (int*)(ws + 3 * seg16 + 131072);    // N+1
  int* deg    = off + (N + 1);                      // N
  int* rank   = deg + N;                            // E
  int* ssrc   = rank + E;                           // E

  int eblk = (E + 255) / 256;
  k_prepw<<<64, 256, 0, stream>>>(W_edge, W1, W2, wimg);
  hipMemsetAsync(deg, 0, (size_t)N * sizeof(int), stream);
  k_gemm_hist<<<nblk + 576, 256, 0, stream>>>(vf, wimg, P16, vf16, N, ei, deg,
                                              rank, E, nblk);
  k_scan<<<1, 1024, 0, stream>>>(deg, off, N, E);
  k_place<<<eblk, 256, 0, stream>>>(ei, off, rank, ssrc, E);
  k_segmax<<<(N + 15) / 16, 256, 0, stream>>>(P16, off, ssrc, b_edge, A16, N);
  k_mlp12<<<nblk, 256, 0, stream>>>(vf16, A16, wimg, b1, gamma, beta, b2, out, N);
}